// Round 1
// 2666.788 us; speedup vs baseline: 1.0510x; 1.0510x over previous
//
#include <hip/hip_runtime.h>
#include <math.h>

#define BATCH 16
#define SEQ   2048
#define L_INP 256
#define MENC  512
#define HD    1024
#define FM    4096
#define TCH   16
#define NCH   128
#define NROW  (BATCH*NCH)   // 2048 rows, row r = c*16 + b

typedef unsigned short u16;
typedef __attribute__((ext_vector_type(8))) short s8v;   // 8 bf16 (4 VGPRs)
typedef __attribute__((ext_vector_type(4))) float f4v;   // MFMA acc

__device__ inline u16 bf16_rne(float x) {
    unsigned u = __builtin_bit_cast(unsigned, x);
    u += 0x7fff + ((u >> 16) & 1);
    return (u16)(u >> 16);
}
__device__ inline float bf16_tof(u16 h) {
    unsigned u = ((unsigned)h) << 16;
    return __builtin_bit_cast(float, u);
}
__device__ inline void split2(float x, u16& h, u16& l) {
    h = bf16_rne(x);
    l = bf16_rne(x - bf16_tof(h));
}

// direct global->LDS 16B async copy (gfx950). LDS dest is wave-uniform base +
// lane*16 (linear); swizzling is done on the per-lane GLOBAL source address.
__device__ inline void gload_lds16(const u16* g, u16* l) {
    __builtin_amdgcn_global_load_lds(
        (const __attribute__((address_space(1))) void*)g,
        (__attribute__((address_space(3))) void*)l, 16, 0, 0);
}

// ---------------- fp32 tiled GEMM (encoder + tiny epilogue GEMMs) ----------------
#define TS 64
#define KT 16
#define LP 68
__device__ inline float4 add4(float4 a, float4 b) {
    return make_float4(a.x + b.x, a.y + b.y, a.z + b.z, a.w + b.w);
}
// MODE 0: OUT=IN@W   MODE 1: +bias   MODE 2: relu(+bias)
template<int MODE>
__global__ __launch_bounds__(256)
void gemm_k(const float* __restrict__ IN, const float* __restrict__ W,
            float* __restrict__ OUT, const float* __restrict__ BIAS,
            int M, int N, int K, int ldIN)
{
    __shared__ float As[KT][LP];
    __shared__ float Bs[KT][LP];
    const int tid  = threadIdx.x;
    const int tx   = tid & 15, ty = tid >> 4;
    const int col0 = blockIdx.x * TS;
    const int row0 = blockIdx.y * TS;
    const int la_k = tid & 15, la_r = tid >> 4;
    const int lb_j = tid & 63, lb_k = tid >> 6;
    float acc[4][4] = {};

    for (int k0 = 0; k0 < K; k0 += KT) {
        #pragma unroll
        for (int i = 0; i < 4; ++i) {
            int r = la_r + (i << 4);
            int grow = row0 + r;
            float v = 0.f;
            if (grow < M) v = IN[(long)grow * ldIN + k0 + la_k];
            As[la_k][r] = v;
        }
        #pragma unroll
        for (int i = 0; i < 4; ++i) {
            int k = lb_k + (i << 2);
            Bs[k][lb_j] = W[(long)(k0 + k) * N + col0 + lb_j];
        }
        __syncthreads();
        #pragma unroll
        for (int kk = 0; kk < KT; ++kk) {
            float4 av = *(const float4*)&As[kk][ty << 2];
            float4 bv = *(const float4*)&Bs[kk][tx << 2];
            float ar[4] = {av.x, av.y, av.z, av.w};
            float br[4] = {bv.x, bv.y, bv.z, bv.w};
            #pragma unroll
            for (int i = 0; i < 4; ++i)
                #pragma unroll
                for (int j = 0; j < 4; ++j)
                    acc[i][j] = fmaf(ar[i], br[j], acc[i][j]);
        }
        __syncthreads();
    }
    const int jc = col0 + (tx << 2);
    float4 bias4 = make_float4(0.f, 0.f, 0.f, 0.f);
    if constexpr (MODE == 1 || MODE == 2) bias4 = *(const float4*)&BIAS[jc];
    #pragma unroll
    for (int i = 0; i < 4; ++i) {
        int row = row0 + (ty << 2) + i;
        if (row >= M) continue;
        float4 vv = make_float4(acc[i][0], acc[i][1], acc[i][2], acc[i][3]);
        if constexpr (MODE == 1 || MODE == 2) vv = add4(vv, bias4);
        if constexpr (MODE == 2) {
            vv.x = fmaxf(vv.x, 0.f); vv.y = fmaxf(vv.y, 0.f);
            vv.z = fmaxf(vv.z, 0.f); vv.w = fmaxf(vv.w, 0.f);
        }
        *(float4*)&OUT[(long)row * N + jc] = vv;
    }
}

// ---------------- bf16-pair MFMA GEMM: OUT = IN@W, K=N=1024 fixed ----------------
// IN pairs natural [m][k]; W pairs TRANSPOSED [n][k]. 128x128 tile, 256 thr.
// LDS: linear [128][32] u16 per array (global_load_lds direct, 16B/lane).
// Swizzle invariant: LDS slot (r, chunk q) holds global k-chunk q ^ ((r>>1)&3);
// staging applies the XOR on the per-lane global address, fragment ds_reads
// apply the same XOR -> bank-conflict-free both directions.
// MODE 0 (POW):  IN slot (inslot+z), OUT slots (oslot+z): nat + transposed pairs.
// MODE 1 (STEP): Hout fuse: v = acc + Hout[pos(r,t)]; Hout=v; emit state pairs.
// MODE 2 (PFX):  row-shift dshift on IN; v = acc + EX[r] (pair-reconstructed); emit pairs.
// MODE 3 (P3):   row-shift 16; W slot z; Hout[pos(r,z)] += acc.
#define LK 32   // LDS row stride in u16 (64 B)
template<int MODE>
__global__ __launch_bounds__(256)
void pgemm(const u16* __restrict__ INh, const u16* __restrict__ INl,
           const u16* __restrict__ Wh,  const u16* __restrict__ Wl,
           float* __restrict__ HOUT,
           const u16* __restrict__ EXh, const u16* __restrict__ EXl,
           u16* __restrict__ Oh, u16* __restrict__ Ol,
           u16* __restrict__ OTh, u16* __restrict__ OTl,
           int t, int dshift, int inslot, int oslot)
{
    const int tid = threadIdx.x;
    const int z = blockIdx.z;
    if constexpr (MODE == 0) {
        long oin = ((long)(inslot + z)) << 20;
        INh += oin; INl += oin;
        long oo = ((long)(oslot + z)) << 20;
        Oh += oo; Ol += oo; OTh += oo; OTl += oo;
    }
    if constexpr (MODE == 3) {
        long ow = ((long)z) << 20;   // W slot z = A^(z+1)
        Wh += ow; Wl += ow;
    }
    const int row0 = blockIdx.y * 128;
    const int col0 = blockIdx.x * 128;

    __shared__ u16 sAh[128 * LK], sAl[128 * LK], sBh[128 * LK], sBl[128 * LK];

    const int lane = tid & 63;
    const int wv   = tid >> 6;
    const int wrow = (wv >> 1) << 6;
    const int wcol = (wv & 1) << 6;
    const int fl   = lane & 15;
    const int quad = lane >> 4;

    // ---- staging geometry: wave wv stages rows [h*64 + wv*16, +16) of each tile.
    // lane -> (row srow, 16B chunk sq); source chunk is XOR-swizzled.
    const int srow = lane >> 2;               // 0..15
    const int sq   = lane & 3;                // chunk within 64B row
    const int qsw  = sq ^ ((lane >> 3) & 3);  // == sq ^ ((row>>1)&3), since row bits1-2 = srow bits1-2
    long offA[2], offB[2];                    // per-lane global element offsets (u16 units)
    #pragma unroll
    for (int h = 0; h < 2; ++h) {
        int rin = h * 64 + wv * 16 + srow;
        int gA = row0 + rin;
        if constexpr (MODE == 2 || MODE == 3) { gA -= dshift; if (gA < 0) gA = 0; }  // clamped; frag zeroed below
        offA[h] = ((long)gA << 10) + qsw * 8;
        offB[h] = ((long)(col0 + rin) << 10) + qsw * 8;
    }

    // fragment-read swizzled chunk offset (u16 units), loop-invariant
    const int fsw = (quad ^ ((fl >> 1) & 3)) << 3;

    bool dead[4] = {false, false, false, false};
    if constexpr (MODE == 2 || MODE == 3) {
        #pragma unroll
        for (int mt = 0; mt < 4; ++mt)
            dead[mt] = (row0 + wrow + mt * 16 + fl) < dshift;
    }

    f4v acc[4][4] = {};
    const s8v zer = {0, 0, 0, 0, 0, 0, 0, 0};

    for (int k0 = 0; k0 < 1024; k0 += 32) {
        __syncthreads();   // previous iter's fragment reads done
        #pragma unroll
        for (int h = 0; h < 2; ++h) {
            const int lb = (h * 64 + wv * 16) * LK;   // wave-uniform LDS base
            gload_lds16(INh + offA[h] + k0, &sAh[lb]);
            gload_lds16(INl + offA[h] + k0, &sAl[lb]);
            gload_lds16(Wh  + offB[h] + k0, &sBh[lb]);
            gload_lds16(Wl  + offB[h] + k0, &sBl[lb]);
        }
        __syncthreads();   // drains vmcnt: staged tiles visible
        // fragments
        s8v ah[4], al[4], bh[4], bl[4];
        #pragma unroll
        for (int mt = 0; mt < 4; ++mt) {
            int off = (wrow + mt * 16 + fl) * LK + fsw;
            ah[mt] = *(const s8v*)&sAh[off];
            al[mt] = *(const s8v*)&sAl[off];
            if constexpr (MODE == 2 || MODE == 3) {
                if (dead[mt]) { ah[mt] = zer; al[mt] = zer; }
            }
        }
        #pragma unroll
        for (int nt = 0; nt < 4; ++nt) {
            int off = (wcol + nt * 16 + fl) * LK + fsw;
            bh[nt] = *(const s8v*)&sBh[off];
            bl[nt] = *(const s8v*)&sBl[off];
        }
        #pragma unroll
        for (int mt = 0; mt < 4; ++mt)
            #pragma unroll
            for (int nt = 0; nt < 4; ++nt) {
                acc[mt][nt] = __builtin_amdgcn_mfma_f32_16x16x32_bf16(ah[mt], bh[nt], acc[mt][nt], 0, 0, 0);
                acc[mt][nt] = __builtin_amdgcn_mfma_f32_16x16x32_bf16(ah[mt], bl[nt], acc[mt][nt], 0, 0, 0);
                acc[mt][nt] = __builtin_amdgcn_mfma_f32_16x16x32_bf16(al[mt], bh[nt], acc[mt][nt], 0, 0, 0);
            }
    }

    // epilogue: C/D layout col=lane&15, row=quad*4+reg
    #pragma unroll
    for (int mt = 0; mt < 4; ++mt) {
        #pragma unroll
        for (int nt = 0; nt < 4; ++nt) {
            #pragma unroll
            for (int reg = 0; reg < 4; ++reg) {
                int grow = row0 + wrow + mt * 16 + quad * 4 + reg;
                int gcol = col0 + wcol + nt * 16 + fl;
                float v = acc[mt][nt][reg];
                if constexpr (MODE == 0) {
                    u16 h, l; split2(v, h, l);
                    long o  = ((long)grow << 10) + gcol;
                    long ot = ((long)gcol << 10) + grow;
                    Oh[o] = h; Ol[o] = l;
                    OTh[ot] = h; OTl[ot] = l;
                } else if constexpr (MODE == 1) {
                    int b = grow & 15, c = grow >> 4;
                    long exoff = ((long)(b * SEQ + c * TCH + t) << 10) + gcol;
                    v += HOUT[exoff];
                    HOUT[exoff] = v;
                    long o = ((long)grow << 10) + gcol;
                    u16 h, l; split2(v, h, l);
                    Oh[o] = h; Ol[o] = l;
                } else if constexpr (MODE == 2) {
                    long o = ((long)grow << 10) + gcol;
                    v += bf16_tof(EXh[o]) + bf16_tof(EXl[o]);
                    u16 h, l; split2(v, h, l);
                    Oh[o] = h; Ol[o] = l;
                } else {  // P3
                    if (grow >= 16) {
                        int b = grow & 15, c = grow >> 4;
                        long exoff = ((long)(b * SEQ + c * TCH + z) << 10) + gcol;
                        HOUT[exoff] += v;
                    }
                }
            }
        }
    }
}

// split A (input matrix) into nat pairs [m][k] and transposed pairs [n][k], slot 0
__global__ __launch_bounds__(256)
void splitA_k(const float* __restrict__ A, u16* __restrict__ nH, u16* __restrict__ nL,
              u16* __restrict__ tH, u16* __restrict__ tL)
{
    __shared__ unsigned sm[64][65];
    const int r0 = blockIdx.y * 64, c0 = blockIdx.x * 64;
    const int tr = threadIdx.x >> 4;
    const int tc = (threadIdx.x & 15) * 4;
    #pragma unroll
    for (int i = 0; i < 4; ++i) {
        int row = tr + i * 16;
        float4 v = *(const float4*)&A[((long)(r0 + row) << 10) + c0 + tc];
        float vv[4] = {v.x, v.y, v.z, v.w};
        u16 h[4], l[4];
        #pragma unroll
        for (int j = 0; j < 4; ++j) {
            split2(vv[j], h[j], l[j]);
            sm[row][tc + j] = (((unsigned)h[j]) << 16) | l[j];
        }
        long o = ((long)(r0 + row) << 10) + c0 + tc;
        *(uint2*)&nH[o] = make_uint2((unsigned)h[0] | ((unsigned)h[1] << 16),
                                     (unsigned)h[2] | ((unsigned)h[3] << 16));
        *(uint2*)&nL[o] = make_uint2((unsigned)l[0] | ((unsigned)l[1] << 16),
                                     (unsigned)l[2] | ((unsigned)l[3] << 16));
    }
    __syncthreads();
    #pragma unroll
    for (int i = 0; i < 4; ++i) {
        int n = tr + i * 16;
        unsigned p[4];
        #pragma unroll
        for (int j = 0; j < 4; ++j) p[j] = sm[tc + j][n];
        long o = ((long)(c0 + n) << 10) + r0 + tc;
        *(uint2*)&tH[o] = make_uint2((p[0] >> 16) | (p[1] & 0xffff0000u),
                                     (p[2] >> 16) | (p[3] & 0xffff0000u));
        *(uint2*)&tL[o] = make_uint2((p[0] & 0xffffu) | (p[1] << 16),
                                     (p[2] & 0xffffu) | (p[3] << 16));
    }
}

// L0 pairs = split(Hout[b, c*TCH])  (Hout holds bu)
__global__ __launch_bounds__(256)
void gather_bu_p(const float* __restrict__ Hout, u16* __restrict__ Oh, u16* __restrict__ Ol)
{
    long i = (long)blockIdx.x * 256 + threadIdx.x;  // 0 .. 2M
    int r = (int)(i >> 10), col = (int)(i & 1023);
    int b = r & 15, c = r >> 4;
    float v = Hout[((long)(b * SEQ + c * TCH) << 10) + col];
    u16 h, l; split2(v, h, l);
    Oh[i] = h; Ol[i] = l;
}

// LayerNorm in double over z = h_last + residual_last (z^2 ~ 1e54 overflows fp32)
__global__ __launch_bounds__(256)
void ln_k(const u16* __restrict__ Sh, const u16* __restrict__ Sl,
          const float* __restrict__ Rlast,
          const float* __restrict__ g, const float* __restrict__ bta,
          float* __restrict__ zout)
{
    __shared__ double red[256];
    int b = blockIdx.x, tid = threadIdx.x;
    long base = ((long)((NCH - 1) * BATCH + b)) << 10;
    const float* rr = Rlast + b * HD;
    double s = 0.0;
    for (int j = tid; j < HD; j += 256)
        s += (double)(bf16_tof(Sh[base + j]) + bf16_tof(Sl[base + j])) + (double)rr[j];
    red[tid] = s; __syncthreads();
    for (int o = 128; o > 0; o >>= 1) { if (tid < o) red[tid] += red[tid + o]; __syncthreads(); }
    double mu = red[0] * (1.0 / HD);
    __syncthreads();
    double ss = 0.0;
    for (int j = tid; j < HD; j += 256) {
        double zz = (double)(bf16_tof(Sh[base + j]) + bf16_tof(Sl[base + j])) + (double)rr[j] - mu;
        ss += zz * zz;
    }
    red[tid] = ss; __syncthreads();
    for (int o = 128; o > 0; o >>= 1) { if (tid < o) red[tid] += red[tid + o]; __syncthreads(); }
    double inv = 1.0 / sqrt(red[0] * (1.0 / HD) + 1e-5);
    __syncthreads();
    for (int j = tid; j < HD; j += 256) {
        double zz = (double)(bf16_tof(Sh[base + j]) + bf16_tof(Sl[base + j])) + (double)rr[j];
        zout[b * HD + j] = (float)(((zz - mu) * inv) * (double)g[j] + (double)bta[j]);
    }
}

extern "C" void kernel_launch(void* const* d_in, const int* in_sizes, int n_in,
                              void* d_out, int out_size, void* d_ws, size_t ws_size,
                              hipStream_t stream)
{
    const float* x     = (const float*)d_in[0];
    const float* W_enc = (const float*)d_in[1];
    const float* b_enc = (const float*)d_in[2];
    const float* W_B   = (const float*)d_in[3];
    const float* A     = (const float*)d_in[4];
    const float* W_res = (const float*)d_in[5];
    const float* b_res = (const float*)d_in[6];
    const float* ln_g  = (const float*)d_in[7];
    const float* ln_b  = (const float*)d_in[8];
    const float* W1    = (const float*)d_in[9];
    const float* b1    = (const float*)d_in[10];
    const float* W2    = (const float*)d_in[11];
    const float* b2    = (const float*)d_in[12];

    float* out0 = (float*)d_out;
    float* Hout = out0 + (long)BATCH * HD;     // (16,2048,1024): holds bu, then H_seq_pre

    // workspace carve (~205 MB)
    char* p = (char*)d_ws;
    auto alloc = [&](size_t bytes) { void* r = (void*)p; p += (bytes + 255) & ~(size_t)255; return r; };
    const long M2 = 1L << 20;                  // elements per power slot
    u16* natH = (u16*)alloc(22 * M2 * 2);      // slots 0..15: A^1..A^16; 16..21: A^32..A^1024
    u16* natL = (u16*)alloc(22 * M2 * 2);
    u16* trH  = (u16*)alloc(22 * M2 * 2);
    u16* trL  = (u16*)alloc(22 * M2 * 2);
    const long SB = (long)NROW * HD;           // 2M state elements
    u16* SPh[3]; u16* SPl[3];
    for (int i = 0; i < 3; ++i) { SPh[i] = (u16*)alloc(SB * 2); SPl[i] = (u16*)alloc(SB * 2); }
    float* Wf    = (float*)alloc((long)L_INP * HD * 4);
    float* bf    = (float*)alloc(HD * 4);
    float* Rlast = (float*)alloc(BATCH * HD * 4);
    float* zln   = (float*)alloc(BATCH * HD * 4);
    float* t1    = (float*)alloc((long)BATCH * FM * 4);

    dim3 blk(256);
    const long MS = (long)BATCH * SEQ;  // 32768

    // --- Encoder (fp32): Hout = x @ (W_enc@W_B) + b_enc@W_B   (= Bu) ---
    gemm_k<0><<<dim3(HD / TS, L_INP / TS), blk, 0, stream>>>(W_enc, W_B, Wf, nullptr, L_INP, HD, MENC, MENC);
    gemm_k<0><<<dim3(HD / TS, 1), blk, 0, stream>>>(b_enc, W_B, bf, nullptr, 1, HD, MENC, MENC);
    gemm_k<1><<<dim3(HD / TS, MS / TS), blk, 0, stream>>>(x, Wf, Hout, bf, (int)MS, HD, L_INP, L_INP);

    // --- split A into slot 0 ---
    splitA_k<<<dim3(16, 16), blk, 0, stream>>>(A, natH, natL, trH, trL);

    // --- powers via pair-MFMA doubling: slot s = A^(s+1) ---
    // R1: slot1 = slot0 @ A^1
    pgemm<0><<<dim3(8, 8, 1), blk, 0, stream>>>(natH, natL, trH, trL, nullptr, nullptr, nullptr,
                                                natH, natL, trH, trL, 0, 0, 0, 1);
    // R2: slots2,3 = slots0,1 @ A^2
    pgemm<0><<<dim3(8, 8, 2), blk, 0, stream>>>(natH, natL, trH + (1L << 20), trL + (1L << 20), nullptr, nullptr, nullptr,
                                                natH, natL, trH, trL, 0, 0, 0, 2);
    // R3: slots4..7 = slots0..3 @ A^4
    pgemm<0><<<dim3(8, 8, 4), blk, 0, stream>>>(natH, natL, trH + (3L << 20), trL + (3L << 20), nullptr, nullptr, nullptr,
                                                natH, natL, trH, trL, 0, 0, 0, 4);
    // R4: slots8..15 = slots0..7 @ A^8
    pgemm<0><<<dim3(8, 8, 8), blk, 0, stream>>>(natH, natL, trH + (7L << 20), trL + (7L << 20), nullptr, nullptr, nullptr,
                                                natH, natL, trH, trL, 0, 0, 0, 8);
    // G-chain: slot16 = A^32 = slot15@slot15; slot16+i = (slot15+i)^2
    for (int i = 0; i < 6; ++i) {
        int src = 15 + i;
        pgemm<0><<<dim3(8, 8, 1), blk, 0, stream>>>(natH, natL, trH + ((long)src << 20), trL + ((long)src << 20),
                                                    nullptr, nullptr, nullptr,
                                                    natH, natL, trH, trL, 0, 0, src, src + 1);
    }

    // --- Pass 1: local chunk scans (states as pairs), fused +bu / Hout scatter ---
    gather_bu_p<<<dim3((int)(SB / 256)), blk, 0, stream>>>(Hout, SPh[0], SPl[0]);
    int cur = 0, nxt = 1;
    for (int t = 1; t < TCH; ++t) {
        pgemm<1><<<dim3(8, 16), blk, 0, stream>>>(SPh[cur], SPl[cur], trH, trL, Hout, nullptr, nullptr,
                                                  SPh[nxt], SPl[nxt], nullptr, nullptr, t, 0, 0, 0);
        int tmp = cur; cur = nxt; nxt = tmp;
    }
    // cur == 1 after 15 steps

    // --- Prefix (7 Hillis-Steele rounds over chunk-end states) ---
    int pin = cur;            // buffer 1
    int tgt[2] = { nxt, 2 };  // {0, 2}
    for (int i = 0; i < 7; ++i) {
        int d = (1 << i) * BATCH;
        int wslot = (i == 0) ? 15 : (16 + i - 1);
        int ob = tgt[i & 1];
        pgemm<2><<<dim3(8, 16), blk, 0, stream>>>(SPh[pin], SPl[pin],
                                                  trH + ((long)wslot << 20), trL + ((long)wslot << 20),
                                                  nullptr, SPh[pin], SPl[pin],
                                                  SPh[ob], SPl[ob], nullptr, nullptr, 0, d, 0, 0);
        pin = ob;
    }
    int Sfin = pin;   // buffer 0 after 7 rounds

    // --- Pass 3 (one launch): Hout[c,z] += Sfin[c-1] @ A^(z+1) ---
    pgemm<3><<<dim3(8, 16, TCH), blk, 0, stream>>>(SPh[Sfin], SPl[Sfin], trH, trL, Hout, nullptr, nullptr,
                                                   nullptr, nullptr, nullptr, nullptr, 0, BATCH, 0, 0);

    // --- Last-token epilogue ---
    gemm_k<1><<<dim3(HD / TS, 1), blk, 0, stream>>>(x + (long)(SEQ - 1) * L_INP, W_res, Rlast, b_res,
                                                    BATCH, HD, L_INP, SEQ * L_INP);
    ln_k<<<dim3(BATCH), blk, 0, stream>>>(SPh[Sfin], SPl[Sfin], Rlast, ln_g, ln_b, zln);
    gemm_k<2><<<dim3(FM / TS, 1), blk, 0, stream>>>(zln, W1, t1, b1, BATCH, FM, HD, HD);
    gemm_k<1><<<dim3(HD / TS, 1), blk, 0, stream>>>(t1, W2, out0, b2, BATCH, HD, FM, FM);
}

// Round 2
// 2318.829 us; speedup vs baseline: 1.2087x; 1.1501x over previous
//
#include <hip/hip_runtime.h>
#include <math.h>

#define BATCH 16
#define SEQ   2048
#define L_INP 256
#define MENC  512
#define HD    1024
#define FM    4096
#define TCH   16
#define NCH   128
#define NROW  (BATCH*NCH)   // 2048 rows, row r = c*16 + b

typedef unsigned short u16;
typedef __attribute__((ext_vector_type(8))) short s8v;   // 8 bf16 (4 VGPRs)
typedef __attribute__((ext_vector_type(4))) float f4v;   // MFMA acc

__device__ inline u16 bf16_rne(float x) {
    unsigned u = __builtin_bit_cast(unsigned, x);
    u += 0x7fff + ((u >> 16) & 1);
    return (u16)(u >> 16);
}
__device__ inline float bf16_tof(u16 h) {
    unsigned u = ((unsigned)h) << 16;
    return __builtin_bit_cast(float, u);
}
__device__ inline void split2(float x, u16& h, u16& l) {
    h = bf16_rne(x);
    l = bf16_rne(x - bf16_tof(h));
}

// direct global->LDS 16B async copy (gfx950). LDS dest is wave-uniform base +
// lane*16 (linear); swizzling is done on the per-lane GLOBAL source address.
__device__ inline void gload_lds16(const u16* g, u16* l) {
    __builtin_amdgcn_global_load_lds(
        (const __attribute__((address_space(1))) void*)g,
        (__attribute__((address_space(3))) void*)l, 16, 0, 0);
}

// ---------------- fp32 tiled GEMM (encoder + Wf precompute) ----------------
#define TS 64
#define KT 16
#define LP 68
__device__ inline float4 add4(float4 a, float4 b) {
    return make_float4(a.x + b.x, a.y + b.y, a.z + b.z, a.w + b.w);
}
// MODE 0: OUT=IN@W   MODE 1: +bias   MODE 2: relu(+bias)
template<int MODE>
__global__ __launch_bounds__(256)
void gemm_k(const float* __restrict__ IN, const float* __restrict__ W,
            float* __restrict__ OUT, const float* __restrict__ BIAS,
            int M, int N, int K, int ldIN)
{
    __shared__ float As[KT][LP];
    __shared__ float Bs[KT][LP];
    const int tid  = threadIdx.x;
    const int tx   = tid & 15, ty = tid >> 4;
    const int col0 = blockIdx.x * TS;
    const int row0 = blockIdx.y * TS;
    const int la_k = tid & 15, la_r = tid >> 4;
    const int lb_j = tid & 63, lb_k = tid >> 6;
    float acc[4][4] = {};

    for (int k0 = 0; k0 < K; k0 += KT) {
        #pragma unroll
        for (int i = 0; i < 4; ++i) {
            int r = la_r + (i << 4);
            int grow = row0 + r;
            float v = 0.f;
            if (grow < M) v = IN[(long)grow * ldIN + k0 + la_k];
            As[la_k][r] = v;
        }
        #pragma unroll
        for (int i = 0; i < 4; ++i) {
            int k = lb_k + (i << 2);
            Bs[k][lb_j] = W[(long)(k0 + k) * N + col0 + lb_j];
        }
        __syncthreads();
        #pragma unroll
        for (int kk = 0; kk < KT; ++kk) {
            float4 av = *(const float4*)&As[kk][ty << 2];
            float4 bv = *(const float4*)&Bs[kk][tx << 2];
            float ar[4] = {av.x, av.y, av.z, av.w};
            float br[4] = {bv.x, bv.y, bv.z, bv.w};
            #pragma unroll
            for (int i = 0; i < 4; ++i)
                #pragma unroll
                for (int j = 0; j < 4; ++j)
                    acc[i][j] = fmaf(ar[i], br[j], acc[i][j]);
        }
        __syncthreads();
    }
    const int jc = col0 + (tx << 2);
    float4 bias4 = make_float4(0.f, 0.f, 0.f, 0.f);
    if constexpr (MODE == 1 || MODE == 2) bias4 = *(const float4*)&BIAS[jc];
    #pragma unroll
    for (int i = 0; i < 4; ++i) {
        int row = row0 + (ty << 2) + i;
        if (row >= M) continue;
        float4 vv = make_float4(acc[i][0], acc[i][1], acc[i][2], acc[i][3]);
        if constexpr (MODE == 1 || MODE == 2) vv = add4(vv, bias4);
        if constexpr (MODE == 2) {
            vv.x = fmaxf(vv.x, 0.f); vv.y = fmaxf(vv.y, 0.f);
            vv.z = fmaxf(vv.z, 0.f); vv.w = fmaxf(vv.w, 0.f);
        }
        *(float4*)&OUT[(long)row * N + jc] = vv;
    }
}

// ---------------- split-K thin-M GEMM (M<=16): PART[p][m][N] = IN@W chunk ----------------
// grid (N/64, K/KC), 256 thr = 16 m-rows x 16 col-quads. W streamed coalesced
// float4, 4 FMA per load; IN chunk (16xKC) in LDS, broadcast reads.
template<int KC>
__global__ __launch_bounds__(256)
void skgemm(const float* __restrict__ IN, const float* __restrict__ W,
            float* __restrict__ PART, int M, int N, int ldIN)
{
    const int tid = threadIdx.x;
    const int m   = tid >> 4;                  // 0..15
    const int cq  = tid & 15;                  // 0..15
    const int col = blockIdx.x * 64 + cq * 4;
    const int p   = blockIdx.y;
    const int k0  = p * KC;
    __shared__ float sIN[16 * KC];
    #pragma unroll
    for (int i = tid; i < 16 * KC; i += 256) {
        int mm = i / KC, kk = i - mm * KC;
        sIN[i] = (mm < M) ? IN[(long)mm * ldIN + k0 + kk] : 0.f;
    }
    __syncthreads();
    float4 acc = make_float4(0.f, 0.f, 0.f, 0.f);
    const float* wp = W + (long)k0 * N + col;
    #pragma unroll 4
    for (int k = 0; k < KC; ++k) {
        float a = sIN[m * KC + k];
        float4 w4 = *(const float4*)&wp[(long)k * N];
        acc.x = fmaf(a, w4.x, acc.x);
        acc.y = fmaf(a, w4.y, acc.y);
        acc.z = fmaf(a, w4.z, acc.z);
        acc.w = fmaf(a, w4.w, acc.w);
    }
    *(float4*)&PART[((long)p * 16 + m) * N + col] = acc;
}

// reduce P partials; MODE 0: none, 1: +bias, 2: relu(+bias)
template<int MODE>
__global__ __launch_bounds__(256)
void skred(const float* __restrict__ PART, const float* __restrict__ BIAS,
           float* __restrict__ OUT, int M, int N, int P)
{
    long i = (long)blockIdx.x * 256 + threadIdx.x;
    if (i >= (long)M * N) return;
    int mm = (int)(i / N), n = (int)(i - (long)mm * N);
    float s = 0.f;
    for (int p = 0; p < P; ++p) s += PART[((long)p * 16 + mm) * N + n];
    if constexpr (MODE == 1 || MODE == 2) s += BIAS[n];
    if constexpr (MODE == 2) s = fmaxf(s, 0.f);
    OUT[(long)mm * N + n] = s;
}

// ---------------- bf16-pair MFMA GEMM: OUT = IN@W, K=N=1024 fixed ----------------
// IN pairs natural [m][k]; W pairs TRANSPOSED [n][k]. 128x128 tile, 256 thr.
// LDS: linear [128][32] u16 per array (global_load_lds direct, 16B/lane).
// Swizzle invariant: LDS slot (r, chunk q) holds global k-chunk q ^ ((r>>1)&3);
// staging applies the XOR on the per-lane global address, fragment ds_reads
// apply the same XOR -> bank-conflict-free both directions.
// MODE 0 (POW):  IN slot (inslot+z), OUT slots (oslot+z): nat + transposed pairs.
// MODE 1 (STEP): Hout fuse: v = acc + Hout[pos(r,t)]; Hout=v; emit state pairs.
// MODE 2 (PFX):  row-shift dshift on IN; v = acc + EX[r] (pair-reconstructed); emit pairs.
// MODE 3 (P3):   row-shift 16; W slot z; Hout[pos(r,z)] += acc.
#define LK 32   // LDS row stride in u16 (64 B)
template<int MODE>
__global__ __launch_bounds__(256)
void pgemm(const u16* __restrict__ INh, const u16* __restrict__ INl,
           const u16* __restrict__ Wh,  const u16* __restrict__ Wl,
           float* __restrict__ HOUT,
           const u16* __restrict__ EXh, const u16* __restrict__ EXl,
           u16* __restrict__ Oh, u16* __restrict__ Ol,
           u16* __restrict__ OTh, u16* __restrict__ OTl,
           int t, int dshift, int inslot, int oslot)
{
    const int tid = threadIdx.x;
    const int z = blockIdx.z;
    if constexpr (MODE == 0) {
        long oin = ((long)(inslot + z)) << 20;
        INh += oin; INl += oin;
        long oo = ((long)(oslot + z)) << 20;
        Oh += oo; Ol += oo; OTh += oo; OTl += oo;
    }
    if constexpr (MODE == 3) {
        long ow = ((long)z) << 20;   // W slot z = A^(z+1)
        Wh += ow; Wl += ow;
    }
    const int row0 = blockIdx.y * 128;
    const int col0 = blockIdx.x * 128;

    __shared__ u16 sAh[128 * LK], sAl[128 * LK], sBh[128 * LK], sBl[128 * LK];

    const int lane = tid & 63;
    const int wv   = tid >> 6;
    const int wrow = (wv >> 1) << 6;
    const int wcol = (wv & 1) << 6;
    const int fl   = lane & 15;
    const int quad = lane >> 4;

    // ---- staging geometry: wave wv stages rows [h*64 + wv*16, +16) of each tile.
    // lane -> (row srow, 16B chunk sq); source chunk is XOR-swizzled.
    const int srow = lane >> 2;               // 0..15
    const int sq   = lane & 3;                // chunk within 64B row
    const int qsw  = sq ^ ((lane >> 3) & 3);  // == sq ^ ((row>>1)&3), since row bits1-2 = srow bits1-2
    long offA[2], offB[2];                    // per-lane global element offsets (u16 units)
    #pragma unroll
    for (int h = 0; h < 2; ++h) {
        int rin = h * 64 + wv * 16 + srow;
        int gA = row0 + rin;
        if constexpr (MODE == 2 || MODE == 3) { gA -= dshift; if (gA < 0) gA = 0; }  // clamped; frag zeroed below
        offA[h] = ((long)gA << 10) + qsw * 8;
        offB[h] = ((long)(col0 + rin) << 10) + qsw * 8;
    }

    // fragment-read swizzled chunk offset (u16 units), loop-invariant
    const int fsw = (quad ^ ((fl >> 1) & 3)) << 3;

    bool dead[4] = {false, false, false, false};
    if constexpr (MODE == 2 || MODE == 3) {
        #pragma unroll
        for (int mt = 0; mt < 4; ++mt)
            dead[mt] = (row0 + wrow + mt * 16 + fl) < dshift;
    }

    f4v acc[4][4] = {};
    const s8v zer = {0, 0, 0, 0, 0, 0, 0, 0};

    for (int k0 = 0; k0 < 1024; k0 += 32) {
        __syncthreads();   // previous iter's fragment reads done
        #pragma unroll
        for (int h = 0; h < 2; ++h) {
            const int lb = (h * 64 + wv * 16) * LK;   // wave-uniform LDS base
            gload_lds16(INh + offA[h] + k0, &sAh[lb]);
            gload_lds16(INl + offA[h] + k0, &sAl[lb]);
            gload_lds16(Wh  + offB[h] + k0, &sBh[lb]);
            gload_lds16(Wl  + offB[h] + k0, &sBl[lb]);
        }
        __syncthreads();   // drains vmcnt: staged tiles visible
        // fragments
        s8v ah[4], al[4], bh[4], bl[4];
        #pragma unroll
        for (int mt = 0; mt < 4; ++mt) {
            int off = (wrow + mt * 16 + fl) * LK + fsw;
            ah[mt] = *(const s8v*)&sAh[off];
            al[mt] = *(const s8v*)&sAl[off];
            if constexpr (MODE == 2 || MODE == 3) {
                if (dead[mt]) { ah[mt] = zer; al[mt] = zer; }
            }
        }
        #pragma unroll
        for (int nt = 0; nt < 4; ++nt) {
            int off = (wcol + nt * 16 + fl) * LK + fsw;
            bh[nt] = *(const s8v*)&sBh[off];
            bl[nt] = *(const s8v*)&sBl[off];
        }
        #pragma unroll
        for (int mt = 0; mt < 4; ++mt)
            #pragma unroll
            for (int nt = 0; nt < 4; ++nt) {
                acc[mt][nt] = __builtin_amdgcn_mfma_f32_16x16x32_bf16(ah[mt], bh[nt], acc[mt][nt], 0, 0, 0);
                acc[mt][nt] = __builtin_amdgcn_mfma_f32_16x16x32_bf16(ah[mt], bl[nt], acc[mt][nt], 0, 0, 0);
                acc[mt][nt] = __builtin_amdgcn_mfma_f32_16x16x32_bf16(al[mt], bh[nt], acc[mt][nt], 0, 0, 0);
            }
    }

    // epilogue: C/D layout col=lane&15, row=quad*4+reg
    #pragma unroll
    for (int mt = 0; mt < 4; ++mt) {
        #pragma unroll
        for (int nt = 0; nt < 4; ++nt) {
            #pragma unroll
            for (int reg = 0; reg < 4; ++reg) {
                int grow = row0 + wrow + mt * 16 + quad * 4 + reg;
                int gcol = col0 + wcol + nt * 16 + fl;
                float v = acc[mt][nt][reg];
                if constexpr (MODE == 0) {
                    u16 h, l; split2(v, h, l);
                    long o  = ((long)grow << 10) + gcol;
                    long ot = ((long)gcol << 10) + grow;
                    Oh[o] = h; Ol[o] = l;
                    OTh[ot] = h; OTl[ot] = l;
                } else if constexpr (MODE == 1) {
                    int b = grow & 15, c = grow >> 4;
                    long exoff = ((long)(b * SEQ + c * TCH + t) << 10) + gcol;
                    v += HOUT[exoff];
                    HOUT[exoff] = v;
                    long o = ((long)grow << 10) + gcol;
                    u16 h, l; split2(v, h, l);
                    Oh[o] = h; Ol[o] = l;
                } else if constexpr (MODE == 2) {
                    long o = ((long)grow << 10) + gcol;
                    v += bf16_tof(EXh[o]) + bf16_tof(EXl[o]);
                    u16 h, l; split2(v, h, l);
                    Oh[o] = h; Ol[o] = l;
                } else {  // P3
                    if (grow >= 16) {
                        int b = grow & 15, c = grow >> 4;
                        long exoff = ((long)(b * SEQ + c * TCH + z) << 10) + gcol;
                        HOUT[exoff] += v;
                    }
                }
            }
        }
    }
}

// split A (input matrix) into nat pairs [m][k] and transposed pairs [n][k], slot 0
__global__ __launch_bounds__(256)
void splitA_k(const float* __restrict__ A, u16* __restrict__ nH, u16* __restrict__ nL,
              u16* __restrict__ tH, u16* __restrict__ tL)
{
    __shared__ unsigned sm[64][65];
    const int r0 = blockIdx.y * 64, c0 = blockIdx.x * 64;
    const int tr = threadIdx.x >> 4;
    const int tc = (threadIdx.x & 15) * 4;
    #pragma unroll
    for (int i = 0; i < 4; ++i) {
        int row = tr + i * 16;
        float4 v = *(const float4*)&A[((long)(r0 + row) << 10) + c0 + tc];
        float vv[4] = {v.x, v.y, v.z, v.w};
        u16 h[4], l[4];
        #pragma unroll
        for (int j = 0; j < 4; ++j) {
            split2(vv[j], h[j], l[j]);
            sm[row][tc + j] = (((unsigned)h[j]) << 16) | l[j];
        }
        long o = ((long)(r0 + row) << 10) + c0 + tc;
        *(uint2*)&nH[o] = make_uint2((unsigned)h[0] | ((unsigned)h[1] << 16),
                                     (unsigned)h[2] | ((unsigned)h[3] << 16));
        *(uint2*)&nL[o] = make_uint2((unsigned)l[0] | ((unsigned)l[1] << 16),
                                     (unsigned)l[2] | ((unsigned)l[3] << 16));
    }
    __syncthreads();
    #pragma unroll
    for (int i = 0; i < 4; ++i) {
        int n = tr + i * 16;
        unsigned p[4];
        #pragma unroll
        for (int j = 0; j < 4; ++j) p[j] = sm[tc + j][n];
        long o = ((long)(c0 + n) << 10) + r0 + tc;
        *(uint2*)&tH[o] = make_uint2((p[0] >> 16) | (p[1] & 0xffff0000u),
                                     (p[2] >> 16) | (p[3] & 0xffff0000u));
        *(uint2*)&tL[o] = make_uint2((p[0] & 0xffffu) | (p[1] << 16),
                                     (p[2] & 0xffffu) | (p[3] << 16));
    }
}

// L0 pairs = split(Hout[b, c*TCH])  (Hout holds bu)
__global__ __launch_bounds__(256)
void gather_bu_p(const float* __restrict__ Hout, u16* __restrict__ Oh, u16* __restrict__ Ol)
{
    long i = (long)blockIdx.x * 256 + threadIdx.x;  // 0 .. 2M
    int r = (int)(i >> 10), col = (int)(i & 1023);
    int b = r & 15, c = r >> 4;
    float v = Hout[((long)(b * SEQ + c * TCH) << 10) + col];
    u16 h, l; split2(v, h, l);
    Oh[i] = h; Ol[i] = l;
}

// LayerNorm in double over z = h_last + residual_last (z^2 ~ 1e54 overflows fp32)
__global__ __launch_bounds__(256)
void ln_k(const u16* __restrict__ Sh, const u16* __restrict__ Sl,
          const float* __restrict__ Rlast,
          const float* __restrict__ g, const float* __restrict__ bta,
          float* __restrict__ zout)
{
    __shared__ double red[256];
    int b = blockIdx.x, tid = threadIdx.x;
    long base = ((long)((NCH - 1) * BATCH + b)) << 10;
    const float* rr = Rlast + b * HD;
    double s = 0.0;
    for (int j = tid; j < HD; j += 256)
        s += (double)(bf16_tof(Sh[base + j]) + bf16_tof(Sl[base + j])) + (double)rr[j];
    red[tid] = s; __syncthreads();
    for (int o = 128; o > 0; o >>= 1) { if (tid < o) red[tid] += red[tid + o]; __syncthreads(); }
    double mu = red[0] * (1.0 / HD);
    __syncthreads();
    double ss = 0.0;
    for (int j = tid; j < HD; j += 256) {
        double zz = (double)(bf16_tof(Sh[base + j]) + bf16_tof(Sl[base + j])) + (double)rr[j] - mu;
        ss += zz * zz;
    }
    red[tid] = ss; __syncthreads();
    for (int o = 128; o > 0; o >>= 1) { if (tid < o) red[tid] += red[tid + o]; __syncthreads(); }
    double inv = 1.0 / sqrt(red[0] * (1.0 / HD) + 1e-5);
    __syncthreads();
    for (int j = tid; j < HD; j += 256) {
        double zz = (double)(bf16_tof(Sh[base + j]) + bf16_tof(Sl[base + j])) + (double)rr[j];
        zout[b * HD + j] = (float)(((zz - mu) * inv) * (double)g[j] + (double)bta[j]);
    }
}

extern "C" void kernel_launch(void* const* d_in, const int* in_sizes, int n_in,
                              void* d_out, int out_size, void* d_ws, size_t ws_size,
                              hipStream_t stream)
{
    const float* x     = (const float*)d_in[0];
    const float* W_enc = (const float*)d_in[1];
    const float* b_enc = (const float*)d_in[2];
    const float* W_B   = (const float*)d_in[3];
    const float* A     = (const float*)d_in[4];
    const float* W_res = (const float*)d_in[5];
    const float* b_res = (const float*)d_in[6];
    const float* ln_g  = (const float*)d_in[7];
    const float* ln_b  = (const float*)d_in[8];
    const float* W1    = (const float*)d_in[9];
    const float* b1    = (const float*)d_in[10];
    const float* W2    = (const float*)d_in[11];
    const float* b2    = (const float*)d_in[12];

    float* out0 = (float*)d_out;
    float* Hout = out0 + (long)BATCH * HD;     // (16,2048,1024): holds bu, then H_seq_pre

    // workspace carve (~207 MB)
    char* p = (char*)d_ws;
    auto alloc = [&](size_t bytes) { void* r = (void*)p; p += (bytes + 255) & ~(size_t)255; return r; };
    const long M2 = 1L << 20;                  // elements per power slot
    u16* natH = (u16*)alloc(22 * M2 * 2);      // slots 0..15: A^1..A^16; 16..21: A^32..A^1024
    u16* natL = (u16*)alloc(22 * M2 * 2);
    u16* trH  = (u16*)alloc(22 * M2 * 2);
    u16* trL  = (u16*)alloc(22 * M2 * 2);
    const long SB = (long)NROW * HD;           // 2M state elements
    u16* SPh[3]; u16* SPl[3];
    for (int i = 0; i < 3; ++i) { SPh[i] = (u16*)alloc(SB * 2); SPl[i] = (u16*)alloc(SB * 2); }
    float* Wf    = (float*)alloc((long)L_INP * HD * 4);
    float* bf    = (float*)alloc(HD * 4);
    float* Rlast = (float*)alloc(BATCH * HD * 4);
    float* zln   = (float*)alloc(BATCH * HD * 4);
    float* t1    = (float*)alloc((long)BATCH * FM * 4);
    float* PART  = (float*)alloc(32L * 16 * 4096 * 4);   // split-K partials (8 MB max)

    dim3 blk(256);
    const long MS = (long)BATCH * SEQ;  // 32768

    // --- Encoder (fp32): Hout = x @ (W_enc@W_B) + b_enc@W_B   (= Bu) ---
    gemm_k<0><<<dim3(HD / TS, L_INP / TS), blk, 0, stream>>>(W_enc, W_B, Wf, nullptr, L_INP, HD, MENC, MENC);
    // bf = b_enc @ W_B  (M=1, K=512) via split-K thin GEMM
    skgemm<128><<<dim3(HD / 64, MENC / 128), blk, 0, stream>>>(b_enc, W_B, PART, 1, HD, MENC);
    skred<0><<<dim3((HD + 255) / 256), blk, 0, stream>>>(PART, nullptr, bf, 1, HD, MENC / 128);
    gemm_k<1><<<dim3(HD / TS, MS / TS), blk, 0, stream>>>(x, Wf, Hout, bf, (int)MS, HD, L_INP, L_INP);

    // --- split A into slot 0 ---
    splitA_k<<<dim3(16, 16), blk, 0, stream>>>(A, natH, natL, trH, trL);

    // --- powers via pair-MFMA doubling: slot s = A^(s+1) ---
    // R1: slot1 = slot0 @ A^1
    pgemm<0><<<dim3(8, 8, 1), blk, 0, stream>>>(natH, natL, trH, trL, nullptr, nullptr, nullptr,
                                                natH, natL, trH, trL, 0, 0, 0, 1);
    // R2: slots2,3 = slots0,1 @ A^2
    pgemm<0><<<dim3(8, 8, 2), blk, 0, stream>>>(natH, natL, trH + (1L << 20), trL + (1L << 20), nullptr, nullptr, nullptr,
                                                natH, natL, trH, trL, 0, 0, 0, 2);
    // R3: slots4..7 = slots0..3 @ A^4
    pgemm<0><<<dim3(8, 8, 4), blk, 0, stream>>>(natH, natL, trH + (3L << 20), trL + (3L << 20), nullptr, nullptr, nullptr,
                                                natH, natL, trH, trL, 0, 0, 0, 4);
    // R4: slots8..15 = slots0..7 @ A^8
    pgemm<0><<<dim3(8, 8, 8), blk, 0, stream>>>(natH, natL, trH + (7L << 20), trL + (7L << 20), nullptr, nullptr, nullptr,
                                                natH, natL, trH, trL, 0, 0, 0, 8);
    // G-chain: slot16 = A^32 = slot15@slot15; slot16+i = (slot15+i)^2
    for (int i = 0; i < 6; ++i) {
        int src = 15 + i;
        pgemm<0><<<dim3(8, 8, 1), blk, 0, stream>>>(natH, natL, trH + ((long)src << 20), trL + ((long)src << 20),
                                                    nullptr, nullptr, nullptr,
                                                    natH, natL, trH, trL, 0, 0, src, src + 1);
    }

    // --- Pass 1: local chunk scans (states as pairs), fused +bu / Hout scatter ---
    gather_bu_p<<<dim3((int)(SB / 256)), blk, 0, stream>>>(Hout, SPh[0], SPl[0]);
    int cur = 0, nxt = 1;
    for (int t = 1; t < TCH; ++t) {
        pgemm<1><<<dim3(8, 16), blk, 0, stream>>>(SPh[cur], SPl[cur], trH, trL, Hout, nullptr, nullptr,
                                                  SPh[nxt], SPl[nxt], nullptr, nullptr, t, 0, 0, 0);
        int tmp = cur; cur = nxt; nxt = tmp;
    }
    // cur == 1 after 15 steps

    // --- Prefix (7 Hillis-Steele rounds over chunk-end states) ---
    int pin = cur;            // buffer 1
    int tgt[2] = { nxt, 2 };  // {0, 2}
    for (int i = 0; i < 7; ++i) {
        int d = (1 << i) * BATCH;
        int wslot = (i == 0) ? 15 : (16 + i - 1);
        int ob = tgt[i & 1];
        pgemm<2><<<dim3(8, 16), blk, 0, stream>>>(SPh[pin], SPl[pin],
                                                  trH + ((long)wslot << 20), trL + ((long)wslot << 20),
                                                  nullptr, SPh[pin], SPl[pin],
                                                  SPh[ob], SPl[ob], nullptr, nullptr, 0, d, 0, 0);
        pin = ob;
    }
    int Sfin = pin;   // buffer 0 after 7 rounds

    // --- Pass 3 (one launch): Hout[c,z] += Sfin[c-1] @ A^(z+1) ---
    pgemm<3><<<dim3(8, 16, TCH), blk, 0, stream>>>(SPh[Sfin], SPl[Sfin], trH, trL, Hout, nullptr, nullptr,
                                                   nullptr, nullptr, nullptr, nullptr, 0, BATCH, 0, 0);

    // --- Last-token epilogue (all thin-M GEMMs via split-K) ---
    // Rlast = x[:, SEQ-1, :] @ W_res + b_res   (M=16, K=256)
    skgemm<64><<<dim3(HD / 64, L_INP / 64), blk, 0, stream>>>(x + (long)(SEQ - 1) * L_INP, W_res, PART, BATCH, HD, SEQ * L_INP);
    skred<1><<<dim3((BATCH * HD + 255) / 256), blk, 0, stream>>>(PART, b_res, Rlast, BATCH, HD, L_INP / 64);
    ln_k<<<dim3(BATCH), blk, 0, stream>>>(SPh[Sfin], SPl[Sfin], Rlast, ln_g, ln_b, zln);
    // t1 = relu(zln @ W1 + b1)   (M=16, N=4096, K=1024)
    skgemm<128><<<dim3(FM / 64, HD / 128), blk, 0, stream>>>(zln, W1, PART, BATCH, FM, HD);
    skred<2><<<dim3((BATCH * FM + 255) / 256), blk, 0, stream>>>(PART, b1, t1, BATCH, FM, HD / 128);
    // out = t1 @ W2 + b2   (M=16, N=1024, K=4096)
    skgemm<128><<<dim3(HD / 64, FM / 128), blk, 0, stream>>>(t1, W2, PART, BATCH, HD, FM);
    skred<1><<<dim3((BATCH * HD + 255) / 256), blk, 0, stream>>>(PART, b2, out0, BATCH, HD, FM / 128);
}

// Round 3
// 1600.723 us; speedup vs baseline: 1.7509x; 1.4486x over previous
//
#include <hip/hip_runtime.h>
#include <math.h>

#define BATCH 16
#define SEQ   2048
#define L_INP 256
#define MENC  512
#define HD    1024
#define FM    4096
#define TCH   16
#define NCH   128
#define NROW  (BATCH*NCH)   // 2048 rows, row r = c*16 + b

typedef unsigned short u16;
typedef __attribute__((ext_vector_type(8))) short s8v;   // 8 bf16 (4 VGPRs)
typedef __attribute__((ext_vector_type(4))) float f4v;   // MFMA acc

__device__ inline u16 bf16_rne(float x) {
    unsigned u = __builtin_bit_cast(unsigned, x);
    u += 0x7fff + ((u >> 16) & 1);
    return (u16)(u >> 16);
}
__device__ inline float bf16_tof(u16 h) {
    unsigned u = ((unsigned)h) << 16;
    return __builtin_bit_cast(float, u);
}
__device__ inline void split2(float x, u16& h, u16& l) {
    h = bf16_rne(x);
    l = bf16_rne(x - bf16_tof(h));
}

// direct global->LDS 16B async copy (gfx950). LDS dest is wave-uniform base +
// lane*16 (linear); swizzling is done on the per-lane GLOBAL source address.
__device__ inline void gload_lds16(const u16* g, u16* l) {
    __builtin_amdgcn_global_load_lds(
        (const __attribute__((address_space(1))) void*)g,
        (__attribute__((address_space(3))) void*)l, 16, 0, 0);
}

// ---------------- fp32 tiled GEMM (Wf precompute only) ----------------
#define TS 64
#define KT 16
#define LP 68
__device__ inline float4 add4(float4 a, float4 b) {
    return make_float4(a.x + b.x, a.y + b.y, a.z + b.z, a.w + b.w);
}
// MODE 0: OUT=IN@W   MODE 1: +bias   MODE 2: relu(+bias)
template<int MODE>
__global__ __launch_bounds__(256)
void gemm_k(const float* __restrict__ IN, const float* __restrict__ W,
            float* __restrict__ OUT, const float* __restrict__ BIAS,
            int M, int N, int K, int ldIN)
{
    __shared__ float As[KT][LP];
    __shared__ float Bs[KT][LP];
    const int tid  = threadIdx.x;
    const int tx   = tid & 15, ty = tid >> 4;
    const int col0 = blockIdx.x * TS;
    const int row0 = blockIdx.y * TS;
    const int la_k = tid & 15, la_r = tid >> 4;
    const int lb_j = tid & 63, lb_k = tid >> 6;
    float acc[4][4] = {};

    for (int k0 = 0; k0 < K; k0 += KT) {
        #pragma unroll
        for (int i = 0; i < 4; ++i) {
            int r = la_r + (i << 4);
            int grow = row0 + r;
            float v = 0.f;
            if (grow < M) v = IN[(long)grow * ldIN + k0 + la_k];
            As[la_k][r] = v;
        }
        #pragma unroll
        for (int i = 0; i < 4; ++i) {
            int k = lb_k + (i << 2);
            Bs[k][lb_j] = W[(long)(k0 + k) * N + col0 + lb_j];
        }
        __syncthreads();
        #pragma unroll
        for (int kk = 0; kk < KT; ++kk) {
            float4 av = *(const float4*)&As[kk][ty << 2];
            float4 bv = *(const float4*)&Bs[kk][tx << 2];
            float ar[4] = {av.x, av.y, av.z, av.w};
            float br[4] = {bv.x, bv.y, bv.z, bv.w};
            #pragma unroll
            for (int i = 0; i < 4; ++i)
                #pragma unroll
                for (int j = 0; j < 4; ++j)
                    acc[i][j] = fmaf(ar[i], br[j], acc[i][j]);
        }
        __syncthreads();
    }
    const int jc = col0 + (tx << 2);
    float4 bias4 = make_float4(0.f, 0.f, 0.f, 0.f);
    if constexpr (MODE == 1 || MODE == 2) bias4 = *(const float4*)&BIAS[jc];
    #pragma unroll
    for (int i = 0; i < 4; ++i) {
        int row = row0 + (ty << 2) + i;
        if (row >= M) continue;
        float4 vv = make_float4(acc[i][0], acc[i][1], acc[i][2], acc[i][3]);
        if constexpr (MODE == 1 || MODE == 2) vv = add4(vv, bias4);
        if constexpr (MODE == 2) {
            vv.x = fmaxf(vv.x, 0.f); vv.y = fmaxf(vv.y, 0.f);
            vv.z = fmaxf(vv.z, 0.f); vv.w = fmaxf(vv.w, 0.f);
        }
        *(float4*)&OUT[(long)row * N + jc] = vv;
    }
}

// ---------------- split-K thin-M GEMM (M<=16): PART[p][m][N] = IN@W chunk ----------------
template<int KC>
__global__ __launch_bounds__(256)
void skgemm(const float* __restrict__ IN, const float* __restrict__ W,
            float* __restrict__ PART, int M, int N, int ldIN)
{
    const int tid = threadIdx.x;
    const int m   = tid >> 4;                  // 0..15
    const int cq  = tid & 15;                  // 0..15
    const int col = blockIdx.x * 64 + cq * 4;
    const int p   = blockIdx.y;
    const int k0  = p * KC;
    __shared__ float sIN[16 * KC];
    #pragma unroll
    for (int i = tid; i < 16 * KC; i += 256) {
        int mm = i / KC, kk = i - mm * KC;
        sIN[i] = (mm < M) ? IN[(long)mm * ldIN + k0 + kk] : 0.f;
    }
    __syncthreads();
    float4 acc = make_float4(0.f, 0.f, 0.f, 0.f);
    const float* wp = W + (long)k0 * N + col;
    #pragma unroll 4
    for (int k = 0; k < KC; ++k) {
        float a = sIN[m * KC + k];
        float4 w4 = *(const float4*)&wp[(long)k * N];
        acc.x = fmaf(a, w4.x, acc.x);
        acc.y = fmaf(a, w4.y, acc.y);
        acc.z = fmaf(a, w4.z, acc.z);
        acc.w = fmaf(a, w4.w, acc.w);
    }
    *(float4*)&PART[((long)p * 16 + m) * N + col] = acc;
}

// reduce P partials; MODE 0: none, 1: +bias, 2: relu(+bias)
template<int MODE>
__global__ __launch_bounds__(256)
void skred(const float* __restrict__ PART, const float* __restrict__ BIAS,
           float* __restrict__ OUT, int M, int N, int P)
{
    long i = (long)blockIdx.x * 256 + threadIdx.x;
    if (i >= (long)M * N) return;
    int mm = (int)(i / N), n = (int)(i - (long)mm * N);
    float s = 0.f;
    for (int p = 0; p < P; ++p) s += PART[((long)p * 16 + mm) * N + n];
    if constexpr (MODE == 1 || MODE == 2) s += BIAS[n];
    if constexpr (MODE == 2) s = fmaxf(s, 0.f);
    OUT[(long)mm * N + n] = s;
}

// ---------------- bf16-pair MFMA GEMM: OUT = IN@W, N=1024 fixed, K=KDIM ----------------
// 64x64 tile, 256 thr (4 waves, 2x2), acc[2][2] (16 AGPR), LDS 16 KB.
// IN pairs natural [m][k]; W pairs TRANSPOSED [n][k].
// LDS linear [64][32] u16 per array (global_load_lds direct, 16B/lane);
// k-chunk XOR-swizzle q ^= (row>>1)&3 applied on per-lane GLOBAL src addr and
// identically on fragment ds_read offsets -> conflict-free both directions.
// MODE 0 (POW):  IN slot (inslot+z), OUT slots (oslot+z): nat + transposed pairs.
// MODE 1 (STEP): Hout fuse: v = acc + Hout[pos(r,t)]; Hout=v; emit state pairs.
// MODE 2 (PFX):  row-shift dshift on IN; v = acc + EX[r] (pair-reconstructed); emit pairs.
// MODE 3 (P3):   row-shift dshift; W slot z; Hout[pos(r,z)] += acc.
// MODE 4 (ENC):  v = acc + BIAS[col]; Hout[m][col] = v; rows m%16==0 also emit
//                state pairs at state-row (s + b)  [seed of pass 1].
#define LK 32   // LDS row stride in u16 (64 B)
template<int MODE, int KDIM>
__global__ __launch_bounds__(256)
void pgemm(const u16* __restrict__ INh, const u16* __restrict__ INl,
           const u16* __restrict__ Wh,  const u16* __restrict__ Wl,
           float* __restrict__ HOUT,
           const u16* __restrict__ EXh, const u16* __restrict__ EXl,
           u16* __restrict__ Oh, u16* __restrict__ Ol,
           u16* __restrict__ OTh, u16* __restrict__ OTl,
           const float* __restrict__ BIAS,
           int t, int dshift, int inslot, int oslot)
{
    const int tid = threadIdx.x;
    const int z = blockIdx.z;
    if constexpr (MODE == 0) {
        long oin = ((long)(inslot + z)) << 20;
        INh += oin; INl += oin;
        long oo = ((long)(oslot + z)) << 20;
        Oh += oo; Ol += oo; OTh += oo; OTl += oo;
    }
    if constexpr (MODE == 3) {
        long ow = ((long)z) << 20;   // W slot z = A^(z+1)
        Wh += ow; Wl += ow;
    }
    const int row0 = blockIdx.y * 64;
    const int col0 = blockIdx.x * 64;

    __shared__ u16 sAh[64 * LK], sAl[64 * LK], sBh[64 * LK], sBl[64 * LK];

    const int lane = tid & 63;
    const int wv   = tid >> 6;
    const int wrow = (wv >> 1) << 5;   // 0 or 32
    const int wcol = (wv & 1) << 5;    // 0 or 32
    const int fl   = lane & 15;
    const int quad = lane >> 4;

    // staging: wave wv stages rows [wv*16, wv*16+16) of A and of B.
    const int srow = lane >> 2;               // 0..15
    const int sq   = lane & 3;                // 16B chunk within 64B row
    const int qsw  = sq ^ ((lane >> 3) & 3);  // == sq ^ ((row>>1)&3)
    const int rin  = wv * 16 + srow;
    int gA = row0 + rin;
    if constexpr (MODE == 2 || MODE == 3) { gA -= dshift; if (gA < 0) gA = 0; }  // clamped; frag zeroed
    const long offA = (long)gA * KDIM + qsw * 8;
    const long offB = (long)(col0 + rin) * KDIM + qsw * 8;
    const int  lb   = (wv * 16) * LK;          // wave-uniform LDS base

    // fragment-read swizzled chunk offset (u16 units), loop-invariant
    const int fsw = (quad ^ ((fl >> 1) & 3)) << 3;

    bool dead[2] = {false, false};
    if constexpr (MODE == 2 || MODE == 3) {
        #pragma unroll
        for (int mt = 0; mt < 2; ++mt)
            dead[mt] = (row0 + wrow + mt * 16 + fl) < dshift;
    }

    f4v acc[2][2] = {};
    const s8v zer = {0, 0, 0, 0, 0, 0, 0, 0};

    for (int k0 = 0; k0 < KDIM; k0 += 32) {
        __syncthreads();   // previous iter's fragment reads done
        gload_lds16(INh + offA + k0, &sAh[lb]);
        gload_lds16(INl + offA + k0, &sAl[lb]);
        gload_lds16(Wh  + offB + k0, &sBh[lb]);
        gload_lds16(Wl  + offB + k0, &sBl[lb]);
        __syncthreads();   // drains vmcnt: staged tiles visible
        s8v ah[2], al[2], bh[2], bl[2];
        #pragma unroll
        for (int mt = 0; mt < 2; ++mt) {
            int off = (wrow + mt * 16 + fl) * LK + fsw;
            ah[mt] = *(const s8v*)&sAh[off];
            al[mt] = *(const s8v*)&sAl[off];
            if constexpr (MODE == 2 || MODE == 3) {
                if (dead[mt]) { ah[mt] = zer; al[mt] = zer; }
            }
        }
        #pragma unroll
        for (int nt = 0; nt < 2; ++nt) {
            int off = (wcol + nt * 16 + fl) * LK + fsw;
            bh[nt] = *(const s8v*)&sBh[off];
            bl[nt] = *(const s8v*)&sBl[off];
        }
        #pragma unroll
        for (int mt = 0; mt < 2; ++mt)
            #pragma unroll
            for (int nt = 0; nt < 2; ++nt) {
                acc[mt][nt] = __builtin_amdgcn_mfma_f32_16x16x32_bf16(ah[mt], bh[nt], acc[mt][nt], 0, 0, 0);
                acc[mt][nt] = __builtin_amdgcn_mfma_f32_16x16x32_bf16(ah[mt], bl[nt], acc[mt][nt], 0, 0, 0);
                acc[mt][nt] = __builtin_amdgcn_mfma_f32_16x16x32_bf16(al[mt], bh[nt], acc[mt][nt], 0, 0, 0);
            }
    }

    // epilogue: C/D layout col=lane&15, row=quad*4+reg
    #pragma unroll
    for (int mt = 0; mt < 2; ++mt) {
        #pragma unroll
        for (int nt = 0; nt < 2; ++nt) {
            #pragma unroll
            for (int reg = 0; reg < 4; ++reg) {
                int grow = row0 + wrow + mt * 16 + quad * 4 + reg;
                int gcol = col0 + wcol + nt * 16 + fl;
                float v = acc[mt][nt][reg];
                if constexpr (MODE == 0) {
                    u16 h, l; split2(v, h, l);
                    long o  = ((long)grow << 10) + gcol;
                    long ot = ((long)gcol << 10) + grow;
                    Oh[o] = h; Ol[o] = l;
                    OTh[ot] = h; OTl[ot] = l;
                } else if constexpr (MODE == 1) {
                    int b = grow & 15, c = grow >> 4;
                    long exoff = ((long)(b * SEQ + c * TCH + t) << 10) + gcol;
                    v += HOUT[exoff];
                    HOUT[exoff] = v;
                    long o = ((long)grow << 10) + gcol;
                    u16 h, l; split2(v, h, l);
                    Oh[o] = h; Ol[o] = l;
                } else if constexpr (MODE == 2) {
                    long o = ((long)grow << 10) + gcol;
                    v += bf16_tof(EXh[o]) + bf16_tof(EXl[o]);
                    u16 h, l; split2(v, h, l);
                    Oh[o] = h; Ol[o] = l;
                } else if constexpr (MODE == 3) {
                    if (grow >= 16) {
                        int b = grow & 15, c = grow >> 4;
                        long exoff = ((long)(b * SEQ + c * TCH + z) << 10) + gcol;
                        HOUT[exoff] += v;
                    }
                } else {  // MODE 4: encoder, grow = b*SEQ + s
                    v += BIAS[gcol];
                    HOUT[((long)grow << 10) + gcol] = v;
                    if ((grow & 15) == 0) {          // s%16==0 -> seed state pairs
                        int b = grow >> 11;           // batch
                        int s = grow & (SEQ - 1);     // s, multiple of 16
                        long so = ((long)(s + b) << 10) + gcol;  // state row c*16+b
                        u16 h, l; split2(v, h, l);
                        Oh[so] = h; Ol[so] = l;
                    }
                }
            }
        }
    }
}

// split A (input matrix) into nat pairs [m][k] and transposed pairs [n][k], slot 0
__global__ __launch_bounds__(256)
void splitA_k(const float* __restrict__ A, u16* __restrict__ nH, u16* __restrict__ nL,
              u16* __restrict__ tH, u16* __restrict__ tL)
{
    __shared__ unsigned sm[64][65];
    const int r0 = blockIdx.y * 64, c0 = blockIdx.x * 64;
    const int tr = threadIdx.x >> 4;
    const int tc = (threadIdx.x & 15) * 4;
    #pragma unroll
    for (int i = 0; i < 4; ++i) {
        int row = tr + i * 16;
        float4 v = *(const float4*)&A[((long)(r0 + row) << 10) + c0 + tc];
        float vv[4] = {v.x, v.y, v.z, v.w};
        u16 h[4], l[4];
        #pragma unroll
        for (int j = 0; j < 4; ++j) {
            split2(vv[j], h[j], l[j]);
            sm[row][tc + j] = (((unsigned)h[j]) << 16) | l[j];
        }
        long o = ((long)(r0 + row) << 10) + c0 + tc;
        *(uint2*)&nH[o] = make_uint2((unsigned)h[0] | ((unsigned)h[1] << 16),
                                     (unsigned)h[2] | ((unsigned)h[3] << 16));
        *(uint2*)&nL[o] = make_uint2((unsigned)l[0] | ((unsigned)l[1] << 16),
                                     (unsigned)l[2] | ((unsigned)l[3] << 16));
    }
    __syncthreads();
    #pragma unroll
    for (int i = 0; i < 4; ++i) {
        int n = tr + i * 16;
        unsigned p[4];
        #pragma unroll
        for (int j = 0; j < 4; ++j) p[j] = sm[tc + j][n];
        long o = ((long)(c0 + n) << 10) + r0 + tc;
        *(uint2*)&tH[o] = make_uint2((p[0] >> 16) | (p[1] & 0xffff0000u),
                                     (p[2] >> 16) | (p[3] & 0xffff0000u));
        *(uint2*)&tL[o] = make_uint2((p[0] & 0xffffu) | (p[1] << 16),
                                     (p[2] & 0xffffu) | (p[3] << 16));
    }
}

// split x (fp32, M*K contiguous) into nat pairs, vectorized x4
__global__ __launch_bounds__(256)
void splitX_k(const float* __restrict__ X, u16* __restrict__ xh, u16* __restrict__ xl)
{
    long i4 = (long)blockIdx.x * 256 + threadIdx.x;
    long base = i4 * 4;
    float4 v = *(const float4*)&X[base];
    float vv[4] = {v.x, v.y, v.z, v.w};
    u16 h[4], l[4];
    #pragma unroll
    for (int j = 0; j < 4; ++j) split2(vv[j], h[j], l[j]);
    *(uint2*)&xh[base] = make_uint2((unsigned)h[0] | ((unsigned)h[1] << 16),
                                    (unsigned)h[2] | ((unsigned)h[3] << 16));
    *(uint2*)&xl[base] = make_uint2((unsigned)l[0] | ((unsigned)l[1] << 16),
                                    (unsigned)l[2] | ((unsigned)l[3] << 16));
}

// Wf (fp32 [256][1024]) -> transposed pairs [1024][256]
__global__ __launch_bounds__(256)
void splitWt_k(const float* __restrict__ Wf, u16* __restrict__ th, u16* __restrict__ tl)
{
    int i = blockIdx.x * 256 + threadIdx.x;   // 0..262143, i = n*256 + k
    int n = i >> 8, k = i & 255;
    float v = Wf[((long)k << 10) + n];
    u16 h, l; split2(v, h, l);
    th[i] = h; tl[i] = l;
}

// LayerNorm in double over z = h_last + residual_last (z^2 ~ 1e54 overflows fp32)
__global__ __launch_bounds__(256)
void ln_k(const u16* __restrict__ Sh, const u16* __restrict__ Sl,
          const float* __restrict__ Rlast,
          const float* __restrict__ g, const float* __restrict__ bta,
          float* __restrict__ zout)
{
    __shared__ double red[256];
    int b = blockIdx.x, tid = threadIdx.x;
    long base = ((long)((NCH - 1) * BATCH + b)) << 10;
    const float* rr = Rlast + b * HD;
    double s = 0.0;
    for (int j = tid; j < HD; j += 256)
        s += (double)(bf16_tof(Sh[base + j]) + bf16_tof(Sl[base + j])) + (double)rr[j];
    red[tid] = s; __syncthreads();
    for (int o = 128; o > 0; o >>= 1) { if (tid < o) red[tid] += red[tid + o]; __syncthreads(); }
    double mu = red[0] * (1.0 / HD);
    __syncthreads();
    double ss = 0.0;
    for (int j = tid; j < HD; j += 256) {
        double zz = (double)(bf16_tof(Sh[base + j]) + bf16_tof(Sl[base + j])) + (double)rr[j] - mu;
        ss += zz * zz;
    }
    red[tid] = ss; __syncthreads();
    for (int o = 128; o > 0; o >>= 1) { if (tid < o) red[tid] += red[tid + o]; __syncthreads(); }
    double inv = 1.0 / sqrt(red[0] * (1.0 / HD) + 1e-5);
    __syncthreads();
    for (int j = tid; j < HD; j += 256) {
        double zz = (double)(bf16_tof(Sh[base + j]) + bf16_tof(Sl[base + j])) + (double)rr[j];
        zout[b * HD + j] = (float)(((zz - mu) * inv) * (double)g[j] + (double)bta[j]);
    }
}

extern "C" void kernel_launch(void* const* d_in, const int* in_sizes, int n_in,
                              void* d_out, int out_size, void* d_ws, size_t ws_size,
                              hipStream_t stream)
{
    const float* x     = (const float*)d_in[0];
    const float* W_enc = (const float*)d_in[1];
    const float* b_enc = (const float*)d_in[2];
    const float* W_B   = (const float*)d_in[3];
    const float* A     = (const float*)d_in[4];
    const float* W_res = (const float*)d_in[5];
    const float* b_res = (const float*)d_in[6];
    const float* ln_g  = (const float*)d_in[7];
    const float* ln_b  = (const float*)d_in[8];
    const float* W1    = (const float*)d_in[9];
    const float* b1    = (const float*)d_in[10];
    const float* W2    = (const float*)d_in[11];
    const float* b2    = (const float*)d_in[12];

    float* out0 = (float*)d_out;
    float* Hout = out0 + (long)BATCH * HD;     // (16,2048,1024): holds bu, then H_seq_pre

    // workspace carve (~207 MB)
    char* p = (char*)d_ws;
    auto alloc = [&](size_t bytes) { void* r = (void*)p; p += (bytes + 255) & ~(size_t)255; return r; };
    const long M2 = 1L << 20;                  // elements per power slot
    u16* natH = (u16*)alloc(22 * M2 * 2);      // slots 0..15: A^1..A^16; 16..21: A^32..A^1024
    u16* natL = (u16*)alloc(22 * M2 * 2);
    u16* trH  = (u16*)alloc(22 * M2 * 2);
    u16* trL  = (u16*)alloc(22 * M2 * 2);
    const long SB = (long)NROW * HD;           // 2M state elements
    u16* SPh[3]; u16* SPl[3];
    for (int i = 0; i < 3; ++i) { SPh[i] = (u16*)alloc(SB * 2); SPl[i] = (u16*)alloc(SB * 2); }
    float* Wf    = (float*)alloc((long)L_INP * HD * 4);
    float* bf    = (float*)alloc(HD * 4);
    float* Rlast = (float*)alloc(BATCH * HD * 4);
    float* zln   = (float*)alloc(BATCH * HD * 4);
    float* t1    = (float*)alloc((long)BATCH * FM * 4);
    float* PART  = (float*)alloc(32L * 16 * 4096 * 4);   // split-K partials (8 MB max)

    // transient aliases (dead before splitA/powers write these regions):
    const long MS = (long)BATCH * SEQ;         // 32768
    u16* xh  = natH;                           // 16.8 MB  (natH region is 44 MB)
    u16* xl  = natH + MS * L_INP;              // 16.8 MB
    u16* wth = trH;                            // 0.5 MB   (trH region is 44 MB)
    u16* wtl = trH + (long)HD * L_INP;         // 0.5 MB

    dim3 blk(256);

    // --- Encoder: Hout = x @ (W_enc@W_B) + b_enc@W_B  (= Bu), via pair-MFMA ---
    gemm_k<0><<<dim3(HD / TS, L_INP / TS), blk, 0, stream>>>(W_enc, W_B, Wf, nullptr, L_INP, HD, MENC, MENC);
    skgemm<128><<<dim3(HD / 64, MENC / 128), blk, 0, stream>>>(b_enc, W_B, PART, 1, HD, MENC);
    skred<0><<<dim3((HD + 255) / 256), blk, 0, stream>>>(PART, nullptr, bf, 1, HD, MENC / 128);
    splitWt_k<<<dim3((HD * L_INP) / 256), blk, 0, stream>>>(Wf, wth, wtl);
    splitX_k<<<dim3((int)(MS * L_INP / 4 / 256)), blk, 0, stream>>>(x, xh, xl);
    // encoder MFMA: also seeds SPh[0]/SPl[0] with t=0 rows (bu)
    pgemm<4, L_INP><<<dim3(HD / 64, (int)(MS / 64)), blk, 0, stream>>>(
        xh, xl, wth, wtl, Hout, nullptr, nullptr,
        SPh[0], SPl[0], nullptr, nullptr, bf, 0, 0, 0, 0);

    // --- split A into slot 0 ---
    splitA_k<<<dim3(16, 16), blk, 0, stream>>>(A, natH, natL, trH, trL);

    // --- powers via pair-MFMA doubling: slot s = A^(s+1) ---
    pgemm<0, HD><<<dim3(16, 16, 1), blk, 0, stream>>>(natH, natL, trH, trL, nullptr, nullptr, nullptr,
                                                      natH, natL, trH, trL, nullptr, 0, 0, 0, 1);
    pgemm<0, HD><<<dim3(16, 16, 2), blk, 0, stream>>>(natH, natL, trH + (1L << 20), trL + (1L << 20), nullptr, nullptr, nullptr,
                                                      natH, natL, trH, trL, nullptr, 0, 0, 0, 2);
    pgemm<0, HD><<<dim3(16, 16, 4), blk, 0, stream>>>(natH, natL, trH + (3L << 20), trL + (3L << 20), nullptr, nullptr, nullptr,
                                                      natH, natL, trH, trL, nullptr, 0, 0, 0, 4);
    pgemm<0, HD><<<dim3(16, 16, 8), blk, 0, stream>>>(natH, natL, trH + (7L << 20), trL + (7L << 20), nullptr, nullptr, nullptr,
                                                      natH, natL, trH, trL, nullptr, 0, 0, 0, 8);
    // G-chain: slot16 = A^32 = slot15@slot15; slot16+i = (slot15+i)^2
    for (int i = 0; i < 6; ++i) {
        int src = 15 + i;
        pgemm<0, HD><<<dim3(16, 16, 1), blk, 0, stream>>>(natH, natL, trH + ((long)src << 20), trL + ((long)src << 20),
                                                          nullptr, nullptr, nullptr,
                                                          natH, natL, trH, trL, nullptr, 0, 0, src, src + 1);
    }

    // --- Pass 1: local chunk scans (states as pairs), fused +bu / Hout scatter ---
    int cur = 0, nxt = 1;
    for (int t = 1; t < TCH; ++t) {
        pgemm<1, HD><<<dim3(16, 32), blk, 0, stream>>>(SPh[cur], SPl[cur], trH, trL, Hout, nullptr, nullptr,
                                                       SPh[nxt], SPl[nxt], nullptr, nullptr, nullptr, t, 0, 0, 0);
        int tmp = cur; cur = nxt; nxt = tmp;
    }
    // cur == 1 after 15 steps

    // --- Prefix (7 Hillis-Steele rounds over chunk-end states) ---
    int pin = cur;            // buffer 1
    int tgt[2] = { nxt, 2 };  // {0, 2}
    for (int i = 0; i < 7; ++i) {
        int d = (1 << i) * BATCH;
        int wslot = (i == 0) ? 15 : (16 + i - 1);
        int ob = tgt[i & 1];
        pgemm<2, HD><<<dim3(16, 32), blk, 0, stream>>>(SPh[pin], SPl[pin],
                                                       trH + ((long)wslot << 20), trL + ((long)wslot << 20),
                                                       nullptr, SPh[pin], SPl[pin],
                                                       SPh[ob], SPl[ob], nullptr, nullptr, nullptr, 0, d, 0, 0);
        pin = ob;
    }
    int Sfin = pin;   // buffer 0 after 7 rounds

    // --- Pass 3 (one launch): Hout[c,z] += Sfin[c-1] @ A^(z+1) ---
    pgemm<3, HD><<<dim3(16, 32, TCH), blk, 0, stream>>>(SPh[Sfin], SPl[Sfin], trH, trL, Hout, nullptr, nullptr,
                                                        nullptr, nullptr, nullptr, nullptr, nullptr, 0, BATCH, 0, 0);

    // --- Last-token epilogue (all thin-M GEMMs via split-K) ---
    skgemm<64><<<dim3(HD / 64, L_INP / 64), blk, 0, stream>>>(x + (long)(SEQ - 1) * L_INP, W_res, PART, BATCH, HD, SEQ * L_INP);
    skred<1><<<dim3((BATCH * HD + 255) / 256), blk, 0, stream>>>(PART, b_res, Rlast, BATCH, HD, L_INP / 64);
    ln_k<<<dim3(BATCH), blk, 0, stream>>>(SPh[Sfin], SPl[Sfin], Rlast, ln_g, ln_b, zln);
    skgemm<128><<<dim3(FM / 64, HD / 128), blk, 0, stream>>>(zln, W1, PART, BATCH, FM, HD);
    skred<2><<<dim3((BATCH * FM + 255) / 256), blk, 0, stream>>>(PART, b1, t1, BATCH, FM, HD / 128);
    skgemm<128><<<dim3(HD / 64, FM / 128), blk, 0, stream>>>(t1, W2, PART, BATCH, HD, FM);
    skred<1><<<dim3((BATCH * HD + 255) / 256), blk, 0, stream>>>(PART, b2, out0, BATCH, HD, FM / 128);
}

// Round 4
// 1580.692 us; speedup vs baseline: 1.7731x; 1.0127x over previous
//
#include <hip/hip_runtime.h>
#include <math.h>

#define BATCH 16
#define SEQ   2048
#define L_INP 256
#define MENC  512
#define HD    1024
#define FM    4096
#define TCH   16
#define NCH   128
#define NROW  (BATCH*NCH)   // 2048 rows, row r = c*16 + b

typedef unsigned short u16;
typedef __attribute__((ext_vector_type(8))) short s8v;   // 8 bf16 (4 VGPRs)
typedef __attribute__((ext_vector_type(4))) float f4v;   // MFMA acc

__device__ inline u16 bf16_rne(float x) {
    unsigned u = __builtin_bit_cast(unsigned, x);
    u += 0x7fff + ((u >> 16) & 1);
    return (u16)(u >> 16);
}
__device__ inline float bf16_tof(u16 h) {
    unsigned u = ((unsigned)h) << 16;
    return __builtin_bit_cast(float, u);
}
__device__ inline void split2(float x, u16& h, u16& l) {
    h = bf16_rne(x);
    l = bf16_rne(x - bf16_tof(h));
}

// direct global->LDS 16B async copy (gfx950). LDS dest is wave-uniform base +
// lane*16 (linear); swizzling is done on the per-lane GLOBAL source address.
__device__ inline void gload_lds16(const u16* g, u16* l) {
    __builtin_amdgcn_global_load_lds(
        (const __attribute__((address_space(1))) void*)g,
        (__attribute__((address_space(3))) void*)l, 16, 0, 0);
}

// ---------------- fp32 tiled GEMM (Wf precompute only) ----------------
#define TS 64
#define KT 16
#define LP 68
__device__ inline float4 add4(float4 a, float4 b) {
    return make_float4(a.x + b.x, a.y + b.y, a.z + b.z, a.w + b.w);
}
// MODE 0: OUT=IN@W   MODE 1: +bias   MODE 2: relu(+bias)
template<int MODE>
__global__ __launch_bounds__(256)
void gemm_k(const float* __restrict__ IN, const float* __restrict__ W,
            float* __restrict__ OUT, const float* __restrict__ BIAS,
            int M, int N, int K, int ldIN)
{
    __shared__ float As[KT][LP];
    __shared__ float Bs[KT][LP];
    const int tid  = threadIdx.x;
    const int tx   = tid & 15, ty = tid >> 4;
    const int col0 = blockIdx.x * TS;
    const int row0 = blockIdx.y * TS;
    const int la_k = tid & 15, la_r = tid >> 4;
    const int lb_j = tid & 63, lb_k = tid >> 6;
    float acc[4][4] = {};

    for (int k0 = 0; k0 < K; k0 += KT) {
        #pragma unroll
        for (int i = 0; i < 4; ++i) {
            int r = la_r + (i << 4);
            int grow = row0 + r;
            float v = 0.f;
            if (grow < M) v = IN[(long)grow * ldIN + k0 + la_k];
            As[la_k][r] = v;
        }
        #pragma unroll
        for (int i = 0; i < 4; ++i) {
            int k = lb_k + (i << 2);
            Bs[k][lb_j] = W[(long)(k0 + k) * N + col0 + lb_j];
        }
        __syncthreads();
        #pragma unroll
        for (int kk = 0; kk < KT; ++kk) {
            float4 av = *(const float4*)&As[kk][ty << 2];
            float4 bv = *(const float4*)&Bs[kk][tx << 2];
            float ar[4] = {av.x, av.y, av.z, av.w};
            float br[4] = {bv.x, bv.y, bv.z, bv.w};
            #pragma unroll
            for (int i = 0; i < 4; ++i)
                #pragma unroll
                for (int j = 0; j < 4; ++j)
                    acc[i][j] = fmaf(ar[i], br[j], acc[i][j]);
        }
        __syncthreads();
    }
    const int jc = col0 + (tx << 2);
    float4 bias4 = make_float4(0.f, 0.f, 0.f, 0.f);
    if constexpr (MODE == 1 || MODE == 2) bias4 = *(const float4*)&BIAS[jc];
    #pragma unroll
    for (int i = 0; i < 4; ++i) {
        int row = row0 + (ty << 2) + i;
        if (row >= M) continue;
        float4 vv = make_float4(acc[i][0], acc[i][1], acc[i][2], acc[i][3]);
        if constexpr (MODE == 1 || MODE == 2) vv = add4(vv, bias4);
        if constexpr (MODE == 2) {
            vv.x = fmaxf(vv.x, 0.f); vv.y = fmaxf(vv.y, 0.f);
            vv.z = fmaxf(vv.z, 0.f); vv.w = fmaxf(vv.w, 0.f);
        }
        *(float4*)&OUT[(long)row * N + jc] = vv;
    }
}

// ---------------- split-K thin-M GEMM (M<=16): PART[p][m][N] = IN@W chunk ----------------
template<int KC>
__global__ __launch_bounds__(256)
void skgemm(const float* __restrict__ IN, const float* __restrict__ W,
            float* __restrict__ PART, int M, int N, int ldIN)
{
    const int tid = threadIdx.x;
    const int m   = tid >> 4;                  // 0..15
    const int cq  = tid & 15;                  // 0..15
    const int col = blockIdx.x * 64 + cq * 4;
    const int p   = blockIdx.y;
    const int k0  = p * KC;
    __shared__ float sIN[16 * KC];
    #pragma unroll
    for (int i = tid; i < 16 * KC; i += 256) {
        int mm = i / KC, kk = i - mm * KC;
        sIN[i] = (mm < M) ? IN[(long)mm * ldIN + k0 + kk] : 0.f;
    }
    __syncthreads();
    float4 acc = make_float4(0.f, 0.f, 0.f, 0.f);
    const float* wp = W + (long)k0 * N + col;
    #pragma unroll 4
    for (int k = 0; k < KC; ++k) {
        float a = sIN[m * KC + k];
        float4 w4 = *(const float4*)&wp[(long)k * N];
        acc.x = fmaf(a, w4.x, acc.x);
        acc.y = fmaf(a, w4.y, acc.y);
        acc.z = fmaf(a, w4.z, acc.z);
        acc.w = fmaf(a, w4.w, acc.w);
    }
    *(float4*)&PART[((long)p * 16 + m) * N + col] = acc;
}

// reduce P partials; MODE 0: none, 1: +bias, 2: relu(+bias)
template<int MODE>
__global__ __launch_bounds__(256)
void skred(const float* __restrict__ PART, const float* __restrict__ BIAS,
           float* __restrict__ OUT, int M, int N, int P)
{
    long i = (long)blockIdx.x * 256 + threadIdx.x;
    if (i >= (long)M * N) return;
    int mm = (int)(i / N), n = (int)(i - (long)mm * N);
    float s = 0.f;
    for (int p = 0; p < P; ++p) s += PART[((long)p * 16 + mm) * N + n];
    if constexpr (MODE == 1 || MODE == 2) s += BIAS[n];
    if constexpr (MODE == 2) s = fmaxf(s, 0.f);
    OUT[(long)mm * N + n] = s;
}

// ---------------- bf16-pair MFMA GEMM: OUT = IN@W, N=1024 fixed, K=KDIM ----------------
// BTxBT tile, 256 thr (4 waves, 2x2 quadrants of BT/2), acc[BT/32][BT/32].
// Double-buffered LDS, 2-phase pipeline: issue next-tile global_load_lds,
// compute current tile, vmcnt(0)-drain AFTER compute (latency hidden), raw
// s_barrier (explicit lgkmcnt(0)+sched_barrier before MFMA per rule #18).
// IN pairs natural [m][k]; W pairs TRANSPOSED [n][k].
// k-chunk XOR-swizzle q ^= (row>>1)&3 on per-lane GLOBAL src addr and on
// fragment ds_read offsets -> bank-conflict-free both directions.
// MODE 0 (POW):  IN slot (inslot+z), OUT slots (oslot+z): nat + transposed pairs.
// MODE 1 (STEP): Hout fuse: v = acc + Hout[pos(r,t)]; Hout=v; emit state pairs.
// MODE 2 (PFX):  row-shift dshift on IN; v = acc + EX[r] (pair-reconstructed); emit pairs.
// MODE 3 (P3):   row-shift dshift; W slot z; Hout[pos(r,z)] += acc.
// MODE 4 (ENC):  v = acc + BIAS[col]; Hout[m][col] = v; rows m%16==0 also emit
//                state pairs at state-row (s + b)  [seed of pass 1].
#define LK 32   // LDS row stride in u16 (64 B)
template<int MODE, int KDIM, int BT>
__global__ __launch_bounds__(256)
void pgemm(const u16* __restrict__ INh, const u16* __restrict__ INl,
           const u16* __restrict__ Wh,  const u16* __restrict__ Wl,
           float* __restrict__ HOUT,
           const u16* __restrict__ EXh, const u16* __restrict__ EXl,
           u16* __restrict__ Oh, u16* __restrict__ Ol,
           u16* __restrict__ OTh, u16* __restrict__ OTl,
           const float* __restrict__ BIAS,
           int t, int dshift, int inslot, int oslot)
{
    constexpr int MT  = BT / 32;     // frag tiles per wave per dim (2 or 4)
    constexpr int NG  = BT / 64;     // staging groups (1 or 2)
    constexpr int BUF = BT * LK;     // u16 per array per buffer
    const int tid = threadIdx.x;
    const int z = blockIdx.z;
    if constexpr (MODE == 0) {
        long oin = ((long)(inslot + z)) << 20;
        INh += oin; INl += oin;
        long oo = ((long)(oslot + z)) << 20;
        Oh += oo; Ol += oo; OTh += oo; OTl += oo;
    }
    if constexpr (MODE == 3) {
        long ow = ((long)z) << 20;   // W slot z = A^(z+1)
        Wh += ow; Wl += ow;
    }
    const int row0 = blockIdx.y * BT;
    const int col0 = blockIdx.x * BT;

    __shared__ u16 sAh[2 * BUF], sAl[2 * BUF], sBh[2 * BUF], sBl[2 * BUF];

    const int lane = tid & 63;
    const int wv   = tid >> 6;
    const int wrow = (wv >> 1) * (BT / 2);
    const int wcol = (wv & 1) * (BT / 2);
    const int fl   = lane & 15;
    const int quad = lane >> 4;

    // staging: wave wv stages rows {h*64 + wv*16 + 0..15} per group h.
    const int srow = lane >> 2;               // 0..15
    const int sq   = lane & 3;                // 16B chunk within 64B row
    const int qsw  = sq ^ ((lane >> 3) & 3);  // == sq ^ ((row>>1)&3)
    long offA[NG], offB[NG];
    int  lbs[NG];
    #pragma unroll
    for (int h = 0; h < NG; ++h) {
        int rin = h * 64 + wv * 16 + srow;
        int gA = row0 + rin;
        if constexpr (MODE == 2 || MODE == 3) { gA -= dshift; if (gA < 0) gA = 0; }  // clamped; frag zeroed
        offA[h] = (long)gA * KDIM + qsw * 8;
        offB[h] = (long)(col0 + rin) * KDIM + qsw * 8;
        lbs[h]  = (h * 64 + wv * 16) * LK;
    }

    // fragment-read swizzled chunk offset (u16 units), loop-invariant
    const int fsw = (quad ^ ((fl >> 1) & 3)) << 3;

    bool dead[MT] = {};
    if constexpr (MODE == 2 || MODE == 3) {
        #pragma unroll
        for (int mt = 0; mt < MT; ++mt)
            dead[mt] = (row0 + wrow + mt * 16 + fl) < dshift;
    }

    f4v acc[MT][MT] = {};
    const s8v zer = {0, 0, 0, 0, 0, 0, 0, 0};

    // prologue: stage k0=0 into buffer 0
    #pragma unroll
    for (int h = 0; h < NG; ++h) {
        gload_lds16(INh + offA[h], &sAh[lbs[h]]);
        gload_lds16(INl + offA[h], &sAl[lbs[h]]);
        gload_lds16(Wh  + offB[h], &sBh[lbs[h]]);
        gload_lds16(Wl  + offB[h], &sBl[lbs[h]]);
    }
    asm volatile("s_waitcnt vmcnt(0)" ::: "memory");
    __builtin_amdgcn_s_barrier();

    int cur = 0;
    for (int k0 = 0; k0 < KDIM; k0 += 32) {
        const int cb = cur * BUF;
        const int nb = (cur ^ 1) * BUF;
        if (k0 + 32 < KDIM) {   // issue next-tile loads (async, land in other buffer)
            #pragma unroll
            for (int h = 0; h < NG; ++h) {
                gload_lds16(INh + offA[h] + k0 + 32, &sAh[nb + lbs[h]]);
                gload_lds16(INl + offA[h] + k0 + 32, &sAl[nb + lbs[h]]);
                gload_lds16(Wh  + offB[h] + k0 + 32, &sBh[nb + lbs[h]]);
                gload_lds16(Wl  + offB[h] + k0 + 32, &sBl[nb + lbs[h]]);
            }
        }
        // fragment reads from current buffer
        s8v ah[MT], al[MT], bh[MT], bl[MT];
        #pragma unroll
        for (int mt = 0; mt < MT; ++mt) {
            int off = cb + (wrow + mt * 16 + fl) * LK + fsw;
            ah[mt] = *(const s8v*)&sAh[off];
            al[mt] = *(const s8v*)&sAl[off];
            if constexpr (MODE == 2 || MODE == 3) {
                if (dead[mt]) { ah[mt] = zer; al[mt] = zer; }
            }
        }
        #pragma unroll
        for (int nt = 0; nt < MT; ++nt) {
            int off = cb + (wcol + nt * 16 + fl) * LK + fsw;
            bh[nt] = *(const s8v*)&sBh[off];
            bl[nt] = *(const s8v*)&sBl[off];
        }
        asm volatile("s_waitcnt lgkmcnt(0)" ::: "memory");   // ds_reads complete
        __builtin_amdgcn_sched_barrier(0);                   // rule #18 fence
        #pragma unroll
        for (int mt = 0; mt < MT; ++mt)
            #pragma unroll
            for (int nt = 0; nt < MT; ++nt) {
                acc[mt][nt] = __builtin_amdgcn_mfma_f32_16x16x32_bf16(ah[mt], bh[nt], acc[mt][nt], 0, 0, 0);
                acc[mt][nt] = __builtin_amdgcn_mfma_f32_16x16x32_bf16(ah[mt], bl[nt], acc[mt][nt], 0, 0, 0);
                acc[mt][nt] = __builtin_amdgcn_mfma_f32_16x16x32_bf16(al[mt], bh[nt], acc[mt][nt], 0, 0, 0);
            }
        asm volatile("s_waitcnt vmcnt(0)" ::: "memory");     // next tile landed (hidden under MFMA)
        __builtin_amdgcn_s_barrier();
        cur ^= 1;
    }

    // epilogue: C/D layout col=lane&15, row=quad*4+reg
    #pragma unroll
    for (int mt = 0; mt < MT; ++mt) {
        #pragma unroll
        for (int nt = 0; nt < MT; ++nt) {
            #pragma unroll
            for (int reg = 0; reg < 4; ++reg) {
                int grow = row0 + wrow + mt * 16 + quad * 4 + reg;
                int gcol = col0 + wcol + nt * 16 + fl;
                float v = acc[mt][nt][reg];
                if constexpr (MODE == 0) {
                    u16 h, l; split2(v, h, l);
                    long o  = ((long)grow << 10) + gcol;
                    long ot = ((long)gcol << 10) + grow;
                    Oh[o] = h; Ol[o] = l;
                    OTh[ot] = h; OTl[ot] = l;
                } else if constexpr (MODE == 1) {
                    int b = grow & 15, c = grow >> 4;
                    long exoff = ((long)(b * SEQ + c * TCH + t) << 10) + gcol;
                    v += HOUT[exoff];
                    HOUT[exoff] = v;
                    long o = ((long)grow << 10) + gcol;
                    u16 h, l; split2(v, h, l);
                    Oh[o] = h; Ol[o] = l;
                } else if constexpr (MODE == 2) {
                    long o = ((long)grow << 10) + gcol;
                    v += bf16_tof(EXh[o]) + bf16_tof(EXl[o]);
                    u16 h, l; split2(v, h, l);
                    Oh[o] = h; Ol[o] = l;
                } else if constexpr (MODE == 3) {
                    if (grow >= 16) {
                        int b = grow & 15, c = grow >> 4;
                        long exoff = ((long)(b * SEQ + c * TCH + z) << 10) + gcol;
                        HOUT[exoff] += v;
                    }
                } else {  // MODE 4: encoder, grow = b*SEQ + s
                    v += BIAS[gcol];
                    HOUT[((long)grow << 10) + gcol] = v;
                    if ((grow & 15) == 0) {          // s%16==0 -> seed state pairs
                        int b = grow >> 11;           // batch
                        int s = grow & (SEQ - 1);     // s, multiple of 16
                        long so = ((long)(s + b) << 10) + gcol;  // state row c*16+b
                        u16 h, l; split2(v, h, l);
                        Oh[so] = h; Ol[so] = l;
                    }
                }
            }
        }
    }
}

// split A (input matrix) into nat pairs [m][k] and transposed pairs [n][k], slot 0
__global__ __launch_bounds__(256)
void splitA_k(const float* __restrict__ A, u16* __restrict__ nH, u16* __restrict__ nL,
              u16* __restrict__ tH, u16* __restrict__ tL)
{
    __shared__ unsigned sm[64][65];
    const int r0 = blockIdx.y * 64, c0 = blockIdx.x * 64;
    const int tr = threadIdx.x >> 4;
    const int tc = (threadIdx.x & 15) * 4;
    #pragma unroll
    for (int i = 0; i < 4; ++i) {
        int row = tr + i * 16;
        float4 v = *(const float4*)&A[((long)(r0 + row) << 10) + c0 + tc];
        float vv[4] = {v.x, v.y, v.z, v.w};
        u16 h[4], l[4];
        #pragma unroll
        for (int j = 0; j < 4; ++j) {
            split2(vv[j], h[j], l[j]);
            sm[row][tc + j] = (((unsigned)h[j]) << 16) | l[j];
        }
        long o = ((long)(r0 + row) << 10) + c0 + tc;
        *(uint2*)&nH[o] = make_uint2((unsigned)h[0] | ((unsigned)h[1] << 16),
                                     (unsigned)h[2] | ((unsigned)h[3] << 16));
        *(uint2*)&nL[o] = make_uint2((unsigned)l[0] | ((unsigned)l[1] << 16),
                                     (unsigned)l[2] | ((unsigned)l[3] << 16));
    }
    __syncthreads();
    #pragma unroll
    for (int i = 0; i < 4; ++i) {
        int n = tr + i * 16;
        unsigned p[4];
        #pragma unroll
        for (int j = 0; j < 4; ++j) p[j] = sm[tc + j][n];
        long o = ((long)(c0 + n) << 10) + r0 + tc;
        *(uint2*)&tH[o] = make_uint2((p[0] >> 16) | (p[1] & 0xffff0000u),
                                     (p[2] >> 16) | (p[3] & 0xffff0000u));
        *(uint2*)&tL[o] = make_uint2((p[0] & 0xffffu) | (p[1] << 16),
                                     (p[2] & 0xffffu) | (p[3] << 16));
    }
}

// split x (fp32, M*K contiguous) into nat pairs, vectorized x4
__global__ __launch_bounds__(256)
void splitX_k(const float* __restrict__ X, u16* __restrict__ xh, u16* __restrict__ xl)
{
    long i4 = (long)blockIdx.x * 256 + threadIdx.x;
    long base = i4 * 4;
    float4 v = *(const float4*)&X[base];
    float vv[4] = {v.x, v.y, v.z, v.w};
    u16 h[4], l[4];
    #pragma unroll
    for (int j = 0; j < 4; ++j) split2(vv[j], h[j], l[j]);
    *(uint2*)&xh[base] = make_uint2((unsigned)h[0] | ((unsigned)h[1] << 16),
                                    (unsigned)h[2] | ((unsigned)h[3] << 16));
    *(uint2*)&xl[base] = make_uint2((unsigned)l[0] | ((unsigned)l[1] << 16),
                                    (unsigned)l[2] | ((unsigned)l[3] << 16));
}

// Wf (fp32 [256][1024]) -> transposed pairs [1024][256]
__global__ __launch_bounds__(256)
void splitWt_k(const float* __restrict__ Wf, u16* __restrict__ th, u16* __restrict__ tl)
{
    int i = blockIdx.x * 256 + threadIdx.x;   // 0..262143, i = n*256 + k
    int n = i >> 8, k = i & 255;
    float v = Wf[((long)k << 10) + n];
    u16 h, l; split2(v, h, l);
    th[i] = h; tl[i] = l;
}

// LayerNorm in double over z = h_last + residual_last (z^2 ~ 1e54 overflows fp32)
__global__ __launch_bounds__(256)
void ln_k(const u16* __restrict__ Sh, const u16* __restrict__ Sl,
          const float* __restrict__ Rlast,
          const float* __restrict__ g, const float* __restrict__ bta,
          float* __restrict__ zout)
{
    __shared__ double red[256];
    int b = blockIdx.x, tid = threadIdx.x;
    long base = ((long)((NCH - 1) * BATCH + b)) << 10;
    const float* rr = Rlast + b * HD;
    double s = 0.0;
    for (int j = tid; j < HD; j += 256)
        s += (double)(bf16_tof(Sh[base + j]) + bf16_tof(Sl[base + j])) + (double)rr[j];
    red[tid] = s; __syncthreads();
    for (int o = 128; o > 0; o >>= 1) { if (tid < o) red[tid] += red[tid + o]; __syncthreads(); }
    double mu = red[0] * (1.0 / HD);
    __syncthreads();
    double ss = 0.0;
    for (int j = tid; j < HD; j += 256) {
        double zz = (double)(bf16_tof(Sh[base + j]) + bf16_tof(Sl[base + j])) + (double)rr[j] - mu;
        ss += zz * zz;
    }
    red[tid] = ss; __syncthreads();
    for (int o = 128; o > 0; o >>= 1) { if (tid < o) red[tid] += red[tid + o]; __syncthreads(); }
    double inv = 1.0 / sqrt(red[0] * (1.0 / HD) + 1e-5);
    __syncthreads();
    for (int j = tid; j < HD; j += 256) {
        double zz = (double)(bf16_tof(Sh[base + j]) + bf16_tof(Sl[base + j])) + (double)rr[j];
        zout[b * HD + j] = (float)(((zz - mu) * inv) * (double)g[j] + (double)bta[j]);
    }
}

extern "C" void kernel_launch(void* const* d_in, const int* in_sizes, int n_in,
                              void* d_out, int out_size, void* d_ws, size_t ws_size,
                              hipStream_t stream)
{
    const float* x     = (const float*)d_in[0];
    const float* W_enc = (const float*)d_in[1];
    const float* b_enc = (const float*)d_in[2];
    const float* W_B   = (const float*)d_in[3];
    const float* A     = (const float*)d_in[4];
    const float* W_res = (const float*)d_in[5];
    const float* b_res = (const float*)d_in[6];
    const float* ln_g  = (const float*)d_in[7];
    const float* ln_b  = (const float*)d_in[8];
    const float* W1    = (const float*)d_in[9];
    const float* b1    = (const float*)d_in[10];
    const float* W2    = (const float*)d_in[11];
    const float* b2    = (const float*)d_in[12];

    float* out0 = (float*)d_out;
    float* Hout = out0 + (long)BATCH * HD;     // (16,2048,1024): holds bu, then H_seq_pre

    // workspace carve (~207 MB)
    char* p = (char*)d_ws;
    auto alloc = [&](size_t bytes) { void* r = (void*)p; p += (bytes + 255) & ~(size_t)255; return r; };
    const long M2 = 1L << 20;                  // elements per power slot
    u16* natH = (u16*)alloc(22 * M2 * 2);      // slots 0..15: A^1..A^16; 16..21: A^32..A^1024
    u16* natL = (u16*)alloc(22 * M2 * 2);
    u16* trH  = (u16*)alloc(22 * M2 * 2);
    u16* trL  = (u16*)alloc(22 * M2 * 2);
    const long SB = (long)NROW * HD;           // 2M state elements
    u16* SPh[3]; u16* SPl[3];
    for (int i = 0; i < 3; ++i) { SPh[i] = (u16*)alloc(SB * 2); SPl[i] = (u16*)alloc(SB * 2); }
    float* Wf    = (float*)alloc((long)L_INP * HD * 4);
    float* bf    = (float*)alloc(HD * 4);
    float* Rlast = (float*)alloc(BATCH * HD * 4);
    float* zln   = (float*)alloc(BATCH * HD * 4);
    float* t1    = (float*)alloc((long)BATCH * FM * 4);
    float* PART  = (float*)alloc(32L * 16 * 4096 * 4);   // split-K partials (8 MB max)

    // transient aliases (dead before splitA/powers write these regions):
    const long MS = (long)BATCH * SEQ;         // 32768
    u16* xh  = natH;                           // 16.8 MB  (natH region is 44 MB)
    u16* xl  = natH + MS * L_INP;              // 16.8 MB
    u16* wth = trH;                            // 0.5 MB   (trH region is 44 MB)
    u16* wtl = trH + (long)HD * L_INP;         // 0.5 MB

    dim3 blk(256);

    // --- Encoder: Hout = x @ (W_enc@W_B) + b_enc@W_B  (= Bu), via pair-MFMA ---
    gemm_k<0><<<dim3(HD / TS, L_INP / TS), blk, 0, stream>>>(W_enc, W_B, Wf, nullptr, L_INP, HD, MENC, MENC);
    skgemm<128><<<dim3(HD / 64, MENC / 128), blk, 0, stream>>>(b_enc, W_B, PART, 1, HD, MENC);
    skred<0><<<dim3((HD + 255) / 256), blk, 0, stream>>>(PART, nullptr, bf, 1, HD, MENC / 128);
    splitWt_k<<<dim3((HD * L_INP) / 256), blk, 0, stream>>>(Wf, wth, wtl);
    splitX_k<<<dim3((int)(MS * L_INP / 4 / 256)), blk, 0, stream>>>(x, xh, xl);
    // encoder MFMA (128^2 tile): also seeds SPh[0]/SPl[0] with t=0 rows (bu)
    pgemm<4, L_INP, 128><<<dim3(HD / 128, (int)(MS / 128)), blk, 0, stream>>>(
        xh, xl, wth, wtl, Hout, nullptr, nullptr,
        SPh[0], SPl[0], nullptr, nullptr, bf, 0, 0, 0, 0);

    // --- split A into slot 0 ---
    splitA_k<<<dim3(16, 16), blk, 0, stream>>>(A, natH, natL, trH, trL);

    // --- powers via pair-MFMA doubling: slot s = A^(s+1) ---
    pgemm<0, HD, 64><<<dim3(16, 16, 1), blk, 0, stream>>>(natH, natL, trH, trL, nullptr, nullptr, nullptr,
                                                          natH, natL, trH, trL, nullptr, 0, 0, 0, 1);
    pgemm<0, HD, 64><<<dim3(16, 16, 2), blk, 0, stream>>>(natH, natL, trH + (1L << 20), trL + (1L << 20), nullptr, nullptr, nullptr,
                                                          natH, natL, trH, trL, nullptr, 0, 0, 0, 2);
    pgemm<0, HD, 128><<<dim3(8, 8, 4), blk, 0, stream>>>(natH, natL, trH + (3L << 20), trL + (3L << 20), nullptr, nullptr, nullptr,
                                                         natH, natL, trH, trL, nullptr, 0, 0, 0, 4);
    pgemm<0, HD, 128><<<dim3(8, 8, 8), blk, 0, stream>>>(natH, natL, trH + (7L << 20), trL + (7L << 20), nullptr, nullptr, nullptr,
                                                         natH, natL, trH, trL, nullptr, 0, 0, 0, 8);
    // G-chain: slot16 = A^32 = slot15@slot15; slot16+i = (slot15+i)^2
    for (int i = 0; i < 6; ++i) {
        int src = 15 + i;
        pgemm<0, HD, 64><<<dim3(16, 16, 1), blk, 0, stream>>>(natH, natL, trH + ((long)src << 20), trL + ((long)src << 20),
                                                              nullptr, nullptr, nullptr,
                                                              natH, natL, trH, trL, nullptr, 0, 0, src, src + 1);
    }

    // --- Pass 1: local chunk scans (states as pairs), fused +bu / Hout scatter ---
    int cur = 0, nxt = 1;
    for (int t = 1; t < TCH; ++t) {
        pgemm<1, HD, 64><<<dim3(16, 32), blk, 0, stream>>>(SPh[cur], SPl[cur], trH, trL, Hout, nullptr, nullptr,
                                                           SPh[nxt], SPl[nxt], nullptr, nullptr, nullptr, t, 0, 0, 0);
        int tmp = cur; cur = nxt; nxt = tmp;
    }
    // cur == 1 after 15 steps

    // --- Prefix (7 Hillis-Steele rounds over chunk-end states) ---
    int pin = cur;            // buffer 1
    int tgt[2] = { nxt, 2 };  // {0, 2}
    for (int i = 0; i < 7; ++i) {
        int d = (1 << i) * BATCH;
        int wslot = (i == 0) ? 15 : (16 + i - 1);
        int ob = tgt[i & 1];
        pgemm<2, HD, 64><<<dim3(16, 32), blk, 0, stream>>>(SPh[pin], SPl[pin],
                                                           trH + ((long)wslot << 20), trL + ((long)wslot << 20),
                                                           nullptr, SPh[pin], SPl[pin],
                                                           SPh[ob], SPl[ob], nullptr, nullptr, nullptr, 0, d, 0, 0);
        pin = ob;
    }
    int Sfin = pin;   // buffer 0 after 7 rounds

    // --- Pass 3 (one launch, 128^2 tile): Hout[c,z] += Sfin[c-1] @ A^(z+1) ---
    pgemm<3, HD, 128><<<dim3(8, 16, TCH), blk, 0, stream>>>(SPh[Sfin], SPl[Sfin], trH, trL, Hout, nullptr, nullptr,
                                                            nullptr, nullptr, nullptr, nullptr, nullptr, 0, BATCH, 0, 0);

    // --- Last-token epilogue (all thin-M GEMMs via split-K) ---
    skgemm<64><<<dim3(HD / 64, L_INP / 64), blk, 0, stream>>>(x + (long)(SEQ - 1) * L_INP, W_res, PART, BATCH, HD, SEQ * L_INP);
    skred<1><<<dim3((BATCH * HD + 255) / 256), blk, 0, stream>>>(PART, b_res, Rlast, BATCH, HD, L_INP / 64);
    ln_k<<<dim3(BATCH), blk, 0, stream>>>(SPh[Sfin], SPl[Sfin], Rlast, ln_g, ln_b, zln);
    skgemm<128><<<dim3(FM / 64, HD / 128), blk, 0, stream>>>(zln, W1, PART, BATCH, FM, HD);
    skred<2><<<dim3((BATCH * FM + 255) / 256), blk, 0, stream>>>(PART, b1, t1, BATCH, FM, HD / 128);
    skgemm<128><<<dim3(HD / 64, FM / 128), blk, 0, stream>>>(t1, W2, PART, BATCH, HD, FM);
    skred<1><<<dim3((BATCH * HD + 255) / 256), blk, 0, stream>>>(PART, b2, out0, BATCH, HD, FM / 128);
}

// Round 5
// 1550.455 us; speedup vs baseline: 1.8077x; 1.0195x over previous
//
#include <hip/hip_runtime.h>
#include <math.h>

#define BATCH 16
#define SEQ   2048
#define L_INP 256
#define MENC  512
#define HD    1024
#define FM    4096
#define TCH   16
#define NCH   128
#define NROW  (BATCH*NCH)   // 2048 rows, row r = c*16 + b

typedef unsigned short u16;
typedef __attribute__((ext_vector_type(8))) short s8v;   // 8 bf16 (4 VGPRs)
typedef __attribute__((ext_vector_type(4))) float f4v;   // MFMA acc

__device__ inline u16 bf16_rne(float x) {
    unsigned u = __builtin_bit_cast(unsigned, x);
    u += 0x7fff + ((u >> 16) & 1);
    return (u16)(u >> 16);
}
__device__ inline float bf16_tof(u16 h) {
    unsigned u = ((unsigned)h) << 16;
    return __builtin_bit_cast(float, u);
}
__device__ inline void split2(float x, u16& h, u16& l) {
    h = bf16_rne(x);
    l = bf16_rne(x - bf16_tof(h));
}

// direct global->LDS 16B async copy (gfx950). LDS dest is wave-uniform base +
// lane*16 (linear); swizzling is done on the per-lane GLOBAL source address.
__device__ inline void gload_lds16(const u16* g, u16* l) {
    __builtin_amdgcn_global_load_lds(
        (const __attribute__((address_space(1))) void*)g,
        (__attribute__((address_space(3))) void*)l, 16, 0, 0);
}

// ---------------- fp32 tiled GEMM (Wf precompute only) ----------------
#define TS 64
#define KT 16
#define LP 68
__device__ inline float4 add4(float4 a, float4 b) {
    return make_float4(a.x + b.x, a.y + b.y, a.z + b.z, a.w + b.w);
}
// MODE 0: OUT=IN@W   MODE 1: +bias   MODE 2: relu(+bias)
template<int MODE>
__global__ __launch_bounds__(256)
void gemm_k(const float* __restrict__ IN, const float* __restrict__ W,
            float* __restrict__ OUT, const float* __restrict__ BIAS,
            int M, int N, int K, int ldIN)
{
    __shared__ float As[KT][LP];
    __shared__ float Bs[KT][LP];
    const int tid  = threadIdx.x;
    const int tx   = tid & 15, ty = tid >> 4;
    const int col0 = blockIdx.x * TS;
    const int row0 = blockIdx.y * TS;
    const int la_k = tid & 15, la_r = tid >> 4;
    const int lb_j = tid & 63, lb_k = tid >> 6;
    float acc[4][4] = {};

    for (int k0 = 0; k0 < K; k0 += KT) {
        #pragma unroll
        for (int i = 0; i < 4; ++i) {
            int r = la_r + (i << 4);
            int grow = row0 + r;
            float v = 0.f;
            if (grow < M) v = IN[(long)grow * ldIN + k0 + la_k];
            As[la_k][r] = v;
        }
        #pragma unroll
        for (int i = 0; i < 4; ++i) {
            int k = lb_k + (i << 2);
            Bs[k][lb_j] = W[(long)(k0 + k) * N + col0 + lb_j];
        }
        __syncthreads();
        #pragma unroll
        for (int kk = 0; kk < KT; ++kk) {
            float4 av = *(const float4*)&As[kk][ty << 2];
            float4 bv = *(const float4*)&Bs[kk][tx << 2];
            float ar[4] = {av.x, av.y, av.z, av.w};
            float br[4] = {bv.x, bv.y, bv.z, bv.w};
            #pragma unroll
            for (int i = 0; i < 4; ++i)
                #pragma unroll
                for (int j = 0; j < 4; ++j)
                    acc[i][j] = fmaf(ar[i], br[j], acc[i][j]);
        }
        __syncthreads();
    }
    const int jc = col0 + (tx << 2);
    float4 bias4 = make_float4(0.f, 0.f, 0.f, 0.f);
    if constexpr (MODE == 1 || MODE == 2) bias4 = *(const float4*)&BIAS[jc];
    #pragma unroll
    for (int i = 0; i < 4; ++i) {
        int row = row0 + (ty << 2) + i;
        if (row >= M) continue;
        float4 vv = make_float4(acc[i][0], acc[i][1], acc[i][2], acc[i][3]);
        if constexpr (MODE == 1 || MODE == 2) vv = add4(vv, bias4);
        if constexpr (MODE == 2) {
            vv.x = fmaxf(vv.x, 0.f); vv.y = fmaxf(vv.y, 0.f);
            vv.z = fmaxf(vv.z, 0.f); vv.w = fmaxf(vv.w, 0.f);
        }
        *(float4*)&OUT[(long)row * N + jc] = vv;
    }
}

// ---------------- split-K thin-M GEMM (M<=16): PART[p][m][N] = IN@W chunk ----------------
template<int KC>
__global__ __launch_bounds__(256)
void skgemm(const float* __restrict__ IN, const float* __restrict__ W,
            float* __restrict__ PART, int M, int N, int ldIN)
{
    const int tid = threadIdx.x;
    const int m   = tid >> 4;                  // 0..15
    const int cq  = tid & 15;                  // 0..15
    const int col = blockIdx.x * 64 + cq * 4;
    const int p   = blockIdx.y;
    const int k0  = p * KC;
    __shared__ float sIN[16 * KC];
    #pragma unroll
    for (int i = tid; i < 16 * KC; i += 256) {
        int mm = i / KC, kk = i - mm * KC;
        sIN[i] = (mm < M) ? IN[(long)mm * ldIN + k0 + kk] : 0.f;
    }
    __syncthreads();
    float4 acc = make_float4(0.f, 0.f, 0.f, 0.f);
    const float* wp = W + (long)k0 * N + col;
    #pragma unroll 4
    for (int k = 0; k < KC; ++k) {
        float a = sIN[m * KC + k];
        float4 w4 = *(const float4*)&wp[(long)k * N];
        acc.x = fmaf(a, w4.x, acc.x);
        acc.y = fmaf(a, w4.y, acc.y);
        acc.z = fmaf(a, w4.z, acc.z);
        acc.w = fmaf(a, w4.w, acc.w);
    }
    *(float4*)&PART[((long)p * 16 + m) * N + col] = acc;
}

// reduce P partials; MODE 0: none, 1: +bias, 2: relu(+bias)
template<int MODE>
__global__ __launch_bounds__(256)
void skred(const float* __restrict__ PART, const float* __restrict__ BIAS,
           float* __restrict__ OUT, int M, int N, int P)
{
    long i = (long)blockIdx.x * 256 + threadIdx.x;
    if (i >= (long)M * N) return;
    int mm = (int)(i / N), n = (int)(i - (long)mm * N);
    float s = 0.f;
    for (int p = 0; p < P; ++p) s += PART[((long)p * 16 + mm) * N + n];
    if constexpr (MODE == 1 || MODE == 2) s += BIAS[n];
    if constexpr (MODE == 2) s = fmaxf(s, 0.f);
    OUT[(long)mm * N + n] = s;
}

// ---------------- bf16-pair MFMA GEMM: OUT = IN@W, N=1024 fixed, K=KDIM ----------------
// BTxBT tile, 256 thr (4 waves, 2x2 quadrants of BT/2), acc[BT/32][BT/32].
// SIMPLE single-buffer loop (measured best r2/r3: compiler schedules waitcnts;
// explicit dbuf+asm pipeline regressed via occupancy cliff + order pinning).
// IN pairs natural [m][k]; W pairs TRANSPOSED [n][k].
// k-chunk XOR-swizzle q ^= (row>>1)&3 on per-lane GLOBAL src addr and on
// fragment ds_read offsets -> bank-conflict-free both directions.
// MODE 0 (POW):  IN slot (inslot+z), OUT slots (oslot+z): nat + transposed pairs.
// MODE 1 (STEP): Hout fuse: v = acc + Hout[pos(r,t)]; Hout=v; emit state pairs.
// MODE 2 (PFX):  row-shift dshift on IN; v = acc + EX[r] (pair-reconstructed); emit pairs.
// MODE 3 (P3):   row-shift dshift; W slot z; Hout[pos(r,z)] += acc.
// MODE 4 (ENC):  v = acc + BIAS[col]; Hout[m][col] = v; rows m%16==0 also emit
//                state pairs at state-row (s + b)  [seed of pass 1].
#define LK 32   // LDS row stride in u16 (64 B)
template<int MODE, int KDIM, int BT>
__global__ __launch_bounds__(256)
void pgemm(const u16* __restrict__ INh, const u16* __restrict__ INl,
           const u16* __restrict__ Wh,  const u16* __restrict__ Wl,
           float* __restrict__ HOUT,
           const u16* __restrict__ EXh, const u16* __restrict__ EXl,
           u16* __restrict__ Oh, u16* __restrict__ Ol,
           u16* __restrict__ OTh, u16* __restrict__ OTl,
           const float* __restrict__ BIAS,
           int t, int dshift, int inslot, int oslot)
{
    constexpr int MT  = BT / 32;     // frag tiles per wave per dim (2 or 4)
    constexpr int NG  = BT / 64;     // staging groups (1 or 2)
    const int tid = threadIdx.x;
    const int z = blockIdx.z;
    if constexpr (MODE == 0) {
        long oin = ((long)(inslot + z)) << 20;
        INh += oin; INl += oin;
        long oo = ((long)(oslot + z)) << 20;
        Oh += oo; Ol += oo; OTh += oo; OTl += oo;
    }
    if constexpr (MODE == 3) {
        long ow = ((long)z) << 20;   // W slot z = A^(z+1)
        Wh += ow; Wl += ow;
    }
    const int row0 = blockIdx.y * BT;
    const int col0 = blockIdx.x * BT;

    __shared__ u16 sAh[BT * LK], sAl[BT * LK], sBh[BT * LK], sBl[BT * LK];

    const int lane = tid & 63;
    const int wv   = tid >> 6;
    const int wrow = (wv >> 1) * (BT / 2);
    const int wcol = (wv & 1) * (BT / 2);
    const int fl   = lane & 15;
    const int quad = lane >> 4;

    // staging: wave wv stages rows {h*64 + wv*16 + 0..15} per group h.
    const int srow = lane >> 2;               // 0..15
    const int sq   = lane & 3;                // 16B chunk within 64B row
    const int qsw  = sq ^ ((lane >> 3) & 3);  // == sq ^ ((row>>1)&3)
    long offA[NG], offB[NG];
    int  lbs[NG];
    #pragma unroll
    for (int h = 0; h < NG; ++h) {
        int rin = h * 64 + wv * 16 + srow;
        int gA = row0 + rin;
        if constexpr (MODE == 2 || MODE == 3) { gA -= dshift; if (gA < 0) gA = 0; }  // clamped; frag zeroed
        offA[h] = (long)gA * KDIM + qsw * 8;
        offB[h] = (long)(col0 + rin) * KDIM + qsw * 8;
        lbs[h]  = (h * 64 + wv * 16) * LK;
    }

    // fragment-read swizzled chunk offset (u16 units), loop-invariant
    const int fsw = (quad ^ ((fl >> 1) & 3)) << 3;

    bool dead[MT] = {};
    if constexpr (MODE == 2 || MODE == 3) {
        #pragma unroll
        for (int mt = 0; mt < MT; ++mt)
            dead[mt] = (row0 + wrow + mt * 16 + fl) < dshift;
    }

    f4v acc[MT][MT] = {};
    const s8v zer = {0, 0, 0, 0, 0, 0, 0, 0};

    for (int k0 = 0; k0 < KDIM; k0 += 32) {
        __syncthreads();   // previous iter's fragment reads done
        #pragma unroll
        for (int h = 0; h < NG; ++h) {
            gload_lds16(INh + offA[h] + k0, &sAh[lbs[h]]);
            gload_lds16(INl + offA[h] + k0, &sAl[lbs[h]]);
            gload_lds16(Wh  + offB[h] + k0, &sBh[lbs[h]]);
            gload_lds16(Wl  + offB[h] + k0, &sBl[lbs[h]]);
        }
        __syncthreads();   // drains vmcnt: staged tiles visible
        s8v ah[MT], al[MT], bh[MT], bl[MT];
        #pragma unroll
        for (int mt = 0; mt < MT; ++mt) {
            int off = (wrow + mt * 16 + fl) * LK + fsw;
            ah[mt] = *(const s8v*)&sAh[off];
            al[mt] = *(const s8v*)&sAl[off];
            if constexpr (MODE == 2 || MODE == 3) {
                if (dead[mt]) { ah[mt] = zer; al[mt] = zer; }
            }
        }
        #pragma unroll
        for (int nt = 0; nt < MT; ++nt) {
            int off = (wcol + nt * 16 + fl) * LK + fsw;
            bh[nt] = *(const s8v*)&sBh[off];
            bl[nt] = *(const s8v*)&sBl[off];
        }
        #pragma unroll
        for (int mt = 0; mt < MT; ++mt)
            #pragma unroll
            for (int nt = 0; nt < MT; ++nt) {
                acc[mt][nt] = __builtin_amdgcn_mfma_f32_16x16x32_bf16(ah[mt], bh[nt], acc[mt][nt], 0, 0, 0);
                acc[mt][nt] = __builtin_amdgcn_mfma_f32_16x16x32_bf16(ah[mt], bl[nt], acc[mt][nt], 0, 0, 0);
                acc[mt][nt] = __builtin_amdgcn_mfma_f32_16x16x32_bf16(al[mt], bh[nt], acc[mt][nt], 0, 0, 0);
            }
    }

    // epilogue: C/D layout col=lane&15, row=quad*4+reg
    #pragma unroll
    for (int mt = 0; mt < MT; ++mt) {
        #pragma unroll
        for (int nt = 0; nt < MT; ++nt) {
            #pragma unroll
            for (int reg = 0; reg < 4; ++reg) {
                int grow = row0 + wrow + mt * 16 + quad * 4 + reg;
                int gcol = col0 + wcol + nt * 16 + fl;
                float v = acc[mt][nt][reg];
                if constexpr (MODE == 0) {
                    u16 h, l; split2(v, h, l);
                    long o  = ((long)grow << 10) + gcol;
                    long ot = ((long)gcol << 10) + grow;
                    Oh[o] = h; Ol[o] = l;
                    OTh[ot] = h; OTl[ot] = l;
                } else if constexpr (MODE == 1) {
                    int b = grow & 15, c = grow >> 4;
                    long exoff = ((long)(b * SEQ + c * TCH + t) << 10) + gcol;
                    v += HOUT[exoff];
                    HOUT[exoff] = v;
                    long o = ((long)grow << 10) + gcol;
                    u16 h, l; split2(v, h, l);
                    Oh[o] = h; Ol[o] = l;
                } else if constexpr (MODE == 2) {
                    long o = ((long)grow << 10) + gcol;
                    v += bf16_tof(EXh[o]) + bf16_tof(EXl[o]);
                    u16 h, l; split2(v, h, l);
                    Oh[o] = h; Ol[o] = l;
                } else if constexpr (MODE == 3) {
                    if (grow >= 16) {
                        int b = grow & 15, c = grow >> 4;
                        long exoff = ((long)(b * SEQ + c * TCH + z) << 10) + gcol;
                        HOUT[exoff] += v;
                    }
                } else {  // MODE 4: encoder, grow = b*SEQ + s
                    v += BIAS[gcol];
                    HOUT[((long)grow << 10) + gcol] = v;
                    if ((grow & 15) == 0) {          // s%16==0 -> seed state pairs
                        int b = grow >> 11;           // batch
                        int s = grow & (SEQ - 1);     // s, multiple of 16
                        long so = ((long)(s + b) << 10) + gcol;  // state row c*16+b
                        u16 h, l; split2(v, h, l);
                        Oh[so] = h; Ol[so] = l;
                    }
                }
            }
        }
    }
}

// split A (input matrix) into nat pairs [m][k] and transposed pairs [n][k], slot 0
__global__ __launch_bounds__(256)
void splitA_k(const float* __restrict__ A, u16* __restrict__ nH, u16* __restrict__ nL,
              u16* __restrict__ tH, u16* __restrict__ tL)
{
    __shared__ unsigned sm[64][65];
    const int r0 = blockIdx.y * 64, c0 = blockIdx.x * 64;
    const int tr = threadIdx.x >> 4;
    const int tc = (threadIdx.x & 15) * 4;
    #pragma unroll
    for (int i = 0; i < 4; ++i) {
        int row = tr + i * 16;
        float4 v = *(const float4*)&A[((long)(r0 + row) << 10) + c0 + tc];
        float vv[4] = {v.x, v.y, v.z, v.w};
        u16 h[4], l[4];
        #pragma unroll
        for (int j = 0; j < 4; ++j) {
            split2(vv[j], h[j], l[j]);
            sm[row][tc + j] = (((unsigned)h[j]) << 16) | l[j];
        }
        long o = ((long)(r0 + row) << 10) + c0 + tc;
        *(uint2*)&nH[o] = make_uint2((unsigned)h[0] | ((unsigned)h[1] << 16),
                                     (unsigned)h[2] | ((unsigned)h[3] << 16));
        *(uint2*)&nL[o] = make_uint2((unsigned)l[0] | ((unsigned)l[1] << 16),
                                     (unsigned)l[2] | ((unsigned)l[3] << 16));
    }
    __syncthreads();
    #pragma unroll
    for (int i = 0; i < 4; ++i) {
        int n = tr + i * 16;
        unsigned p[4];
        #pragma unroll
        for (int j = 0; j < 4; ++j) p[j] = sm[tc + j][n];
        long o = ((long)(c0 + n) << 10) + r0 + tc;
        *(uint2*)&tH[o] = make_uint2((p[0] >> 16) | (p[1] & 0xffff0000u),
                                     (p[2] >> 16) | (p[3] & 0xffff0000u));
        *(uint2*)&tL[o] = make_uint2((p[0] & 0xffffu) | (p[1] << 16),
                                     (p[2] & 0xffffu) | (p[3] << 16));
    }
}

// split x (fp32, M*K contiguous) into nat pairs, vectorized x4
__global__ __launch_bounds__(256)
void splitX_k(const float* __restrict__ X, u16* __restrict__ xh, u16* __restrict__ xl)
{
    long i4 = (long)blockIdx.x * 256 + threadIdx.x;
    long base = i4 * 4;
    float4 v = *(const float4*)&X[base];
    float vv[4] = {v.x, v.y, v.z, v.w};
    u16 h[4], l[4];
    #pragma unroll
    for (int j = 0; j < 4; ++j) split2(vv[j], h[j], l[j]);
    *(uint2*)&xh[base] = make_uint2((unsigned)h[0] | ((unsigned)h[1] << 16),
                                    (unsigned)h[2] | ((unsigned)h[3] << 16));
    *(uint2*)&xl[base] = make_uint2((unsigned)l[0] | ((unsigned)l[1] << 16),
                                    (unsigned)l[2] | ((unsigned)l[3] << 16));
}

// Wf (fp32 [256][1024]) -> transposed pairs [1024][256]
__global__ __launch_bounds__(256)
void splitWt_k(const float* __restrict__ Wf, u16* __restrict__ th, u16* __restrict__ tl)
{
    int i = blockIdx.x * 256 + threadIdx.x;   // 0..262143, i = n*256 + k
    int n = i >> 8, k = i & 255;
    float v = Wf[((long)k << 10) + n];
    u16 h, l; split2(v, h, l);
    th[i] = h; tl[i] = l;
}

// LayerNorm in double over z = h_last + residual_last (z^2 ~ 1e54 overflows fp32)
__global__ __launch_bounds__(256)
void ln_k(const u16* __restrict__ Sh, const u16* __restrict__ Sl,
          const float* __restrict__ Rlast,
          const float* __restrict__ g, const float* __restrict__ bta,
          float* __restrict__ zout)
{
    __shared__ double red[256];
    int b = blockIdx.x, tid = threadIdx.x;
    long base = ((long)((NCH - 1) * BATCH + b)) << 10;
    const float* rr = Rlast + b * HD;
    double s = 0.0;
    for (int j = tid; j < HD; j += 256)
        s += (double)(bf16_tof(Sh[base + j]) + bf16_tof(Sl[base + j])) + (double)rr[j];
    red[tid] = s; __syncthreads();
    for (int o = 128; o > 0; o >>= 1) { if (tid < o) red[tid] += red[tid + o]; __syncthreads(); }
    double mu = red[0] * (1.0 / HD);
    __syncthreads();
    double ss = 0.0;
    for (int j = tid; j < HD; j += 256) {
        double zz = (double)(bf16_tof(Sh[base + j]) + bf16_tof(Sl[base + j])) + (double)rr[j] - mu;
        ss += zz * zz;
    }
    red[tid] = ss; __syncthreads();
    for (int o = 128; o > 0; o >>= 1) { if (tid < o) red[tid] += red[tid + o]; __syncthreads(); }
    double inv = 1.0 / sqrt(red[0] * (1.0 / HD) + 1e-5);
    __syncthreads();
    for (int j = tid; j < HD; j += 256) {
        double zz = (double)(bf16_tof(Sh[base + j]) + bf16_tof(Sl[base + j])) + (double)rr[j];
        zout[b * HD + j] = (float)(((zz - mu) * inv) * (double)g[j] + (double)bta[j]);
    }
}

extern "C" void kernel_launch(void* const* d_in, const int* in_sizes, int n_in,
                              void* d_out, int out_size, void* d_ws, size_t ws_size,
                              hipStream_t stream)
{
    const float* x     = (const float*)d_in[0];
    const float* W_enc = (const float*)d_in[1];
    const float* b_enc = (const float*)d_in[2];
    const float* W_B   = (const float*)d_in[3];
    const float* A     = (const float*)d_in[4];
    const float* W_res = (const float*)d_in[5];
    const float* b_res = (const float*)d_in[6];
    const float* ln_g  = (const float*)d_in[7];
    const float* ln_b  = (const float*)d_in[8];
    const float* W1    = (const float*)d_in[9];
    const float* b1    = (const float*)d_in[10];
    const float* W2    = (const float*)d_in[11];
    const float* b2    = (const float*)d_in[12];

    float* out0 = (float*)d_out;
    float* Hout = out0 + (long)BATCH * HD;     // (16,2048,1024): holds bu, then H_seq_pre

    // workspace carve (~207 MB)
    char* p = (char*)d_ws;
    auto alloc = [&](size_t bytes) { void* r = (void*)p; p += (bytes + 255) & ~(size_t)255; return r; };
    const long M2 = 1L << 20;                  // elements per power slot
    u16* natH = (u16*)alloc(22 * M2 * 2);      // slots 0..15: A^1..A^16; 16..21: A^32..A^1024
    u16* natL = (u16*)alloc(22 * M2 * 2);
    u16* trH  = (u16*)alloc(22 * M2 * 2);
    u16* trL  = (u16*)alloc(22 * M2 * 2);
    const long SB = (long)NROW * HD;           // 2M state elements
    u16* SPh[3]; u16* SPl[3];
    for (int i = 0; i < 3; ++i) { SPh[i] = (u16*)alloc(SB * 2); SPl[i] = (u16*)alloc(SB * 2); }
    float* Wf    = (float*)alloc((long)L_INP * HD * 4);
    float* bf    = (float*)alloc(HD * 4);
    float* Rlast = (float*)alloc(BATCH * HD * 4);
    float* zln   = (float*)alloc(BATCH * HD * 4);
    float* t1    = (float*)alloc((long)BATCH * FM * 4);
    float* PART  = (float*)alloc(32L * 16 * 4096 * 4);   // split-K partials (8 MB max)

    // transient aliases (dead before splitA/powers write these regions):
    const long MS = (long)BATCH * SEQ;         // 32768
    u16* xh  = natH;                           // 16.8 MB  (natH region is 44 MB)
    u16* xl  = natH + MS * L_INP;              // 16.8 MB
    u16* wth = trH;                            // 0.5 MB   (trH region is 44 MB)
    u16* wtl = trH + (long)HD * L_INP;         // 0.5 MB

    dim3 blk(256);

    // --- Encoder: Hout = x @ (W_enc@W_B) + b_enc@W_B  (= Bu), via pair-MFMA ---
    gemm_k<0><<<dim3(HD / TS, L_INP / TS), blk, 0, stream>>>(W_enc, W_B, Wf, nullptr, L_INP, HD, MENC, MENC);
    skgemm<128><<<dim3(HD / 64, MENC / 128), blk, 0, stream>>>(b_enc, W_B, PART, 1, HD, MENC);
    skred<0><<<dim3((HD + 255) / 256), blk, 0, stream>>>(PART, nullptr, bf, 1, HD, MENC / 128);
    splitWt_k<<<dim3((HD * L_INP) / 256), blk, 0, stream>>>(Wf, wth, wtl);
    splitX_k<<<dim3((int)(MS * L_INP / 4 / 256)), blk, 0, stream>>>(x, xh, xl);
    // encoder MFMA (128^2 tile, grid 2048): also seeds SPh[0]/SPl[0] with t=0 rows (bu)
    pgemm<4, L_INP, 128><<<dim3(HD / 128, (int)(MS / 128)), blk, 0, stream>>>(
        xh, xl, wth, wtl, Hout, nullptr, nullptr,
        SPh[0], SPl[0], nullptr, nullptr, bf, 0, 0, 0, 0);

    // --- split A into slot 0 ---
    splitA_k<<<dim3(16, 16), blk, 0, stream>>>(A, natH, natL, trH, trL);

    // --- powers via pair-MFMA doubling: slot s = A^(s+1) ---
    pgemm<0, HD, 64><<<dim3(16, 16, 1), blk, 0, stream>>>(natH, natL, trH, trL, nullptr, nullptr, nullptr,
                                                          natH, natL, trH, trL, nullptr, 0, 0, 0, 1);
    pgemm<0, HD, 64><<<dim3(16, 16, 2), blk, 0, stream>>>(natH, natL, trH + (1L << 20), trL + (1L << 20), nullptr, nullptr, nullptr,
                                                          natH, natL, trH, trL, nullptr, 0, 0, 0, 2);
    pgemm<0, HD, 128><<<dim3(8, 8, 4), blk, 0, stream>>>(natH, natL, trH + (3L << 20), trL + (3L << 20), nullptr, nullptr, nullptr,
                                                         natH, natL, trH, trL, nullptr, 0, 0, 0, 4);
    pgemm<0, HD, 128><<<dim3(8, 8, 8), blk, 0, stream>>>(natH, natL, trH + (7L << 20), trL + (7L << 20), nullptr, nullptr, nullptr,
                                                         natH, natL, trH, trL, nullptr, 0, 0, 0, 8);
    // G-chain: slot16 = A^32 = slot15@slot15; slot16+i = (slot15+i)^2
    for (int i = 0; i < 6; ++i) {
        int src = 15 + i;
        pgemm<0, HD, 64><<<dim3(16, 16, 1), blk, 0, stream>>>(natH, natL, trH + ((long)src << 20), trL + ((long)src << 20),
                                                              nullptr, nullptr, nullptr,
                                                              natH, natL, trH, trL, nullptr, 0, 0, src, src + 1);
    }

    // --- Pass 1: local chunk scans (states as pairs), fused +bu / Hout scatter ---
    int cur = 0, nxt = 1;
    for (int t = 1; t < TCH; ++t) {
        pgemm<1, HD, 64><<<dim3(16, 32), blk, 0, stream>>>(SPh[cur], SPl[cur], trH, trL, Hout, nullptr, nullptr,
                                                           SPh[nxt], SPl[nxt], nullptr, nullptr, nullptr, t, 0, 0, 0);
        int tmp = cur; cur = nxt; nxt = tmp;
    }
    // cur == 1 after 15 steps

    // --- Prefix (7 Hillis-Steele rounds over chunk-end states) ---
    int pin = cur;            // buffer 1
    int tgt[2] = { nxt, 2 };  // {0, 2}
    for (int i = 0; i < 7; ++i) {
        int d = (1 << i) * BATCH;
        int wslot = (i == 0) ? 15 : (16 + i - 1);
        int ob = tgt[i & 1];
        pgemm<2, HD, 64><<<dim3(16, 32), blk, 0, stream>>>(SPh[pin], SPl[pin],
                                                           trH + ((long)wslot << 20), trL + ((long)wslot << 20),
                                                           nullptr, SPh[pin], SPl[pin],
                                                           SPh[ob], SPl[ob], nullptr, nullptr, nullptr, 0, d, 0, 0);
        pin = ob;
    }
    int Sfin = pin;   // buffer 0 after 7 rounds

    // --- Pass 3 (one launch, 128^2 tile, grid 2048): Hout[c,z] += Sfin[c-1] @ A^(z+1) ---
    pgemm<3, HD, 128><<<dim3(8, 16, TCH), blk, 0, stream>>>(SPh[Sfin], SPl[Sfin], trH, trL, Hout, nullptr, nullptr,
                                                            nullptr, nullptr, nullptr, nullptr, nullptr, 0, BATCH, 0, 0);

    // --- Last-token epilogue (all thin-M GEMMs via split-K) ---
    skgemm<64><<<dim3(HD / 64, L_INP / 64), blk, 0, stream>>>(x + (long)(SEQ - 1) * L_INP, W_res, PART, BATCH, HD, SEQ * L_INP);
    skred<1><<<dim3((BATCH * HD + 255) / 256), blk, 0, stream>>>(PART, b_res, Rlast, BATCH, HD, L_INP / 64);
    ln_k<<<dim3(BATCH), blk, 0, stream>>>(SPh[Sfin], SPl[Sfin], Rlast, ln_g, ln_b, zln);
    skgemm<128><<<dim3(FM / 64, HD / 128), blk, 0, stream>>>(zln, W1, PART, BATCH, FM, HD);
    skred<2><<<dim3((BATCH * FM + 255) / 256), blk, 0, stream>>>(PART, b1, t1, BATCH, FM, HD / 128);
    skgemm<128><<<dim3(HD / 64, FM / 128), blk, 0, stream>>>(t1, W2, PART, BATCH, HD, FM);
    skred<1><<<dim3((BATCH * HD + 255) / 256), blk, 0, stream>>>(PART, b2, out0, BATCH, HD, FM / 128);
}